// Round 13
// baseline (129.994 us; speedup 1.0000x reference)
//
#include <hip/hip_runtime.h>
#include <math.h>

#define BB 8
#define AA 19248
#define GG 32
#define CC 81
#define PP 32
#define PHW 19044   /* 138*138 */
#define KPOS 128
#define NEGRATIO 3
#define SELCAP 7680
#define NWCH 304    /* 19 outer iters x 16 waves of 64 anchors */
#define NB1 76      /* k1 blocks per image = ceil(AA/256) */
#define NPT 1191    /* pixel tiles of 16 = ceil(PHW/16) */
#define NB7 298     /* k7 blocks per image = ceil(NPT/4) */

typedef _Float16 half8 __attribute__((ext_vector_type(8)));
typedef float floatx4 __attribute__((ext_vector_type(4)));

// ---------------------------------------------------------------------------
// IoU helper — contraction off so every recomputation produces bitwise-
// identical values and FMA fusion can't flip threshold/argmax decisions.
// ---------------------------------------------------------------------------
__device__ __forceinline__ float iou_one(float ax1, float ay1, float ax2, float ay2,
                                         float areaA,
                                         float gx1, float gy1, float gx2, float gy2) {
#pragma clang fp contract(off)
    float ix1 = fmaxf(ax1, gx1), iy1 = fmaxf(ay1, gy1);
    float ix2 = fminf(ax2, gx2), iy2 = fminf(ay2, gy2);
    float iw = fmaxf(ix2 - ix1, 0.0f), ih = fmaxf(iy2 - iy1, 0.0f);
    float inter = iw * ih;
    float areaB = (gx2 - gx1) * (gy2 - gy1);
    float u = areaA + areaB - inter;
    u = fmaxf(u, 1e-6f);
    return inter / u;
}

// ---------------------------------------------------------------------------
// K0: streaming prep — per pixel, (a) pack the 32 binary gt-masks into one
// u32, (b) transpose protos to [b][px][32] f16 (RNE). Round-12's k7 stalled
// ~4k cyc/wave on 40 strided loads with VGPR=28 (no memory-level
// parallelism); this kernel does those gathers ONCE, coalesced both ways,
// at full occupancy. k7's prologue then needs just 2 coalesced loads.
// ---------------------------------------------------------------------------
__global__ __launch_bounds__(256) void k0_prep(
    const float* __restrict__ protos, const float* __restrict__ gtm,
    _Float16* __restrict__ protoT, unsigned* __restrict__ pmask) {
    int b = blockIdx.y;
    int px = blockIdx.x * 256 + threadIdx.x;
    if (px >= PHW) return;
    const float* pb = protos + (size_t)b * PP * PHW + px;
    _Float16 v[PP];
    #pragma unroll
    for (int k = 0; k < PP; ++k)
        v[k] = (_Float16)pb[(size_t)k * PHW];
    half8* dst = (half8*)&protoT[((size_t)b * PHW + px) * PP];
    #pragma unroll
    for (int q = 0; q < 4; ++q)
        dst[q] = *(half8*)&v[q * 8];
    const float* gb = gtm + (size_t)b * GG * PHW + px;
    unsigned m = 0u;
    #pragma unroll
    for (int g = 0; g < GG; ++g)
        m |= (gb[(size_t)g * PHW] > 0.5f) ? (1u << g) : 0u;
    pmask[(size_t)b * PHW + px] = m;
}

// ---------------------------------------------------------------------------
// K1: per (b,a) best IoU + first-max argmax over g, AND per-(b,g) best-anchor
// partial keys per block (value desc, index asc), reduced in K3.
// ---------------------------------------------------------------------------
__global__ __launch_bounds__(256) void k1_match(
    const float* __restrict__ anchors, const float* __restrict__ gt_boxes,
    float* __restrict__ best_iou, int* __restrict__ best_g,
    unsigned long long* __restrict__ gkey_part, float* __restrict__ acc) {
#pragma clang fp contract(off)
    int b = blockIdx.y;
    int a = blockIdx.x * 256 + threadIdx.x;
    int lane = threadIdx.x & 63;
    if (blockIdx.x == 0 && b == 0 && threadIdx.x < 4)
        ((int*)acc)[threadIdx.x] = 0;            // zero [cls, box, mask, npos]
    __shared__ float sg[GG][4];
    __shared__ unsigned long long s_gk[GG];
    for (int t = threadIdx.x; t < GG * 4; t += 256)
        sg[t >> 2][t & 3] = gt_boxes[b * GG * 4 + t] / 550.0f;
    if (threadIdx.x < GG) s_gk[threadIdx.x] = 0ULL;
    __syncthreads();
    bool valid = a < AA;
    int ac = valid ? a : AA - 1;
    float4 an = ((const float4*)anchors)[ac];
    float ax1 = an.x - an.z * 0.5f, ay1 = an.y - an.w * 0.5f;
    float ax2 = an.x + an.z * 0.5f, ay2 = an.y + an.w * 0.5f;
    float areaA = (ax2 - ax1) * (ay2 - ay1);
    unsigned long long bk = 0ULL;   // (vbits<<6)|(31-g): max => first-max argmax
    for (int gg = 0; gg < GG; ++gg) {
        int g = (gg + lane) & (GG - 1);          // stagger: 32 distinct LDS slots
        float v = iou_one(ax1, ay1, ax2, ay2, areaA, sg[g][0], sg[g][1], sg[g][2], sg[g][3]);
        unsigned vb = __float_as_uint(v);        // v >= 0 -> order-preserving
        unsigned long long k2 = ((unsigned long long)vb << 6) | (unsigned)(GG - 1 - g);
        if (k2 > bk) bk = k2;
        if (valid) {
            unsigned long long kg =
                ((unsigned long long)vb << 32) | (unsigned)(AA - 1 - a);
            atomicMax(&s_gk[g], kg);
        }
    }
    if (valid) {
        best_iou[b * AA + a] = __uint_as_float((unsigned)(bk >> 6));
        best_g[b * AA + a] = (GG - 1) - (int)(bk & 63ULL);
    }
    __syncthreads();
    if (threadIdx.x < GG)
        gkey_part[((size_t)b * NB1 + blockIdx.x) * GG + threadIdx.x] = s_gk[threadIdx.x];
}

// ---------------------------------------------------------------------------
// K3: per image — reduce per-block gt keys, scatter overrides via an O(1) LDS
// lookup table (ascending g -> last wins, matching XLA scatter), pos
// compaction + keys, hard-negative cap via ballot-based scan, active-row
// compaction. selmask: 0 = unused, 1 = neg, 2 = pos.
// ---------------------------------------------------------------------------
__global__ __launch_bounds__(1024) void k3_match_scan(
    const float* __restrict__ best_iou, const int* __restrict__ best_g_in,
    const unsigned long long* __restrict__ gkey_part,
    int* __restrict__ gidx_out, int* __restrict__ selmask,
    unsigned long long* __restrict__ pos_key,
    int* __restrict__ pos_cnt, int* __restrict__ g_npos,
    int* __restrict__ act_list, int* __restrict__ act_cnt) {
#pragma clang fp contract(off)
    int b = blockIdx.x;
    int tid = threadIdx.x;
    int lane = tid & 63, wid = tid >> 6;
    __shared__ short s_ov[AA];                  // override g per anchor, -1 none
    __shared__ unsigned long long s_gmax[GG];
    __shared__ int sba[GG];
    __shared__ unsigned long long s_pmask[NWCH];
    __shared__ unsigned long long s_nmask[NWCH];
    __shared__ int s_woff[NWCH];
    __shared__ int s_wred[5];
    __shared__ int s_cnt, s_act;
    for (int i = tid; i < AA; i += 1024) s_ov[i] = -1;
    if (tid < GG) s_gmax[tid] = 0ULL;
    if (tid == 0) { s_cnt = 0; s_act = 0; }
    __syncthreads();
    // reduce 76 per-block partial keys per g (32 g x 32 groups)
    for (int c = tid >> 5; c < NB1; c += 32)
        atomicMax(&s_gmax[tid & 31],
                  gkey_part[((size_t)b * NB1 + c) * GG + (tid & 31)]);
    __syncthreads();
    if (tid < GG) sba[tid] = AA - 1 - (int)(unsigned)(s_gmax[tid] & 0xffffffffULL);
    __syncthreads();
    if (tid == 0) {
        for (int g = 0; g < GG; ++g) s_ov[sba[g]] = (short)g;  // ascending: last wins
    }
    __syncthreads();

    // pass 1: matching decisions + pos keys + per-wave-chunk ballots
    for (int base = 0; base < AA; base += 1024) {
        int a = base + tid;
        bool p = false, npre = false;
        if (a < AA) {
            float biou = best_iou[b * AA + a];
            int ov = s_ov[a];
            int gi = (ov >= 0) ? ov : best_g_in[b * AA + a];
            p = (biou >= 0.5f) || (ov >= 0);
            npre = (biou < 0.4f) && !p;
            gidx_out[b * AA + a] = gi;
            selmask[b * AA + a] = p ? 2 : (npre ? 1 : 0);
            if (p) {
                int slot = atomicAdd(&s_cnt, 1);
                unsigned vb = __float_as_uint(biou + 1.0f);   // >= 0x3F800000
                unsigned long long key =
                    ((unsigned long long)(vb - 0x3F800000u) << 32) |
                    (unsigned)(AA - 1 - a);
                pos_key[(size_t)b * AA + slot] = key;
            }
        }
        unsigned long long pm = __ballot(p);
        unsigned long long nm = __ballot(npre);
        if (lane == 0) {
            int w = (base >> 6) + wid;
            s_pmask[w] = pm;
            s_nmask[w] = nm;
        }
    }
    __syncthreads();
    int npos = s_cnt;
    if (tid == 0) { pos_cnt[b] = npos; atomicAdd(g_npos, npos); }
    int cap = npos * NEGRATIO;

    // scan 304 chunk counts with 5 waves
    int c = (tid < NWCH) ? __popcll(s_nmask[tid]) : 0;
    int inc = c;
    if (wid < 5) {
        #pragma unroll
        for (int d = 1; d < 64; d <<= 1) {
            int t = __shfl_up(inc, d);
            if (lane >= d) inc += t;
        }
        if (lane == 63) s_wred[wid] = inc;
    }
    __syncthreads();
    if (tid == 0) {
        int run = 0;
        #pragma unroll
        for (int i = 0; i < 5; ++i) { int t = s_wred[i]; s_wred[i] = run; run += t; }
    }
    __syncthreads();
    if (tid < NWCH) s_woff[tid] = inc - c + s_wred[wid];   // exclusive prefix
    __syncthreads();

    // pass 2: drop negs beyond cap, compact active rows (order-free)
    for (int base = 0; base < AA; base += 1024) {
        int a = base + tid;
        int w = (base >> 6) + wid;
        unsigned long long nm = s_nmask[w], pm = s_pmask[w];
        bool npre = (nm >> lane) & 1ULL;
        bool pos  = (pm >> lane) & 1ULL;
        int rank = __popcll(nm & ((1ULL << lane) - 1ULL));
        bool kept = npre && (s_woff[w] + rank + 1 <= cap);
        if (a < AA) {
            if (npre && !kept) selmask[b * AA + a] = 0;
            if (pos || kept) {
                int slot = atomicAdd(&s_act, 1);
                act_list[b * AA + slot] = a;
            }
        }
    }
    __syncthreads();
    if (tid == 0) act_cnt[b] = s_act;
}

// ---------------------------------------------------------------------------
// K45: focal classification + box loss fused over the compacted active list.
// ---------------------------------------------------------------------------
#define K45BLK 128
__global__ __launch_bounds__(256) void k45_cls_box(
    const float* __restrict__ cls_p, const int* __restrict__ gtl,
    const int* __restrict__ gidx, const int* __restrict__ selmask,
    const int* __restrict__ act_list, const int* __restrict__ act_cnt,
    const float* __restrict__ box_p, const float* __restrict__ anchors,
    const float* __restrict__ gt_boxes, float* __restrict__ acc) {
    int b = blockIdx.y;
    int n = act_cnt[b];
    int group = blockIdx.x * 4 + (threadIdx.x >> 6);
    int lane = threadIdx.x & 63;
    float fsum = 0.0f, bsum = 0.0f;
    for (int i = group; i < n; i += K45BLK * 4) {
        int a = act_list[b * AA + i];
        int r = b * AA + a;
        const float* x = cls_p + (size_t)r * CC;
        float e0 = x[lane];
        float e1 = (lane < CC - 64) ? x[64 + lane] : -3.0e38f;
        float m = fmaxf(e0, e1);
        for (int off = 32; off; off >>= 1) m = fmaxf(m, __shfl_xor(m, off));
        float s = expf(e0 - m) + ((lane < CC - 64) ? expf(e1 - m) : 0.0f);
        for (int off = 32; off; off >>= 1) s += __shfl_xor(s, off);
        if (lane == 0) {
            int sm = selmask[r];
            int g = gidx[r];
            int lbl = (sm == 2) ? gtl[b * GG + g] : 0;
            float pt = expf(x[lbl] - m) / s;
            pt = fminf(fmaxf(pt, 1e-6f), 1.0f - 1e-6f);
            float at = (lbl > 0) ? 0.25f : 0.75f;
            float om = 1.0f - pt;
            fsum += at * om * om * (-logf(pt));
            if (sm == 2) {
                float m0 = gt_boxes[(b * GG + g) * 4 + 0] / 550.0f;
                float m1 = gt_boxes[(b * GG + g) * 4 + 1] / 550.0f;
                float m2 = gt_boxes[(b * GG + g) * 4 + 2] / 550.0f;
                float m3 = gt_boxes[(b * GG + g) * 4 + 3] / 550.0f;
                float4 an = ((const float4*)anchors)[a];
                float gcx = 0.5f * (m0 + m2), gcy = 0.5f * (m1 + m3);
                float gw = fmaxf(m2 - m0, 1e-6f), gh = fmaxf(m3 - m1, 1e-6f);
                float t0 = (gcx - an.x) / (an.z * 0.1f);
                float t1 = (gcy - an.y) / (an.w * 0.1f);
                float t2 = logf(gw / an.z) / 0.2f;
                float t3 = logf(gh / an.w) / 0.2f;
                const float* bp = box_p + (size_t)r * 4;
                float d;
                d = fabsf(bp[0] - t0); bsum += (d < 1.0f) ? 0.5f * d * d : d - 0.5f;
                d = fabsf(bp[1] - t1); bsum += (d < 1.0f) ? 0.5f * d * d : d - 0.5f;
                d = fabsf(bp[2] - t2); bsum += (d < 1.0f) ? 0.5f * d * d : d - 0.5f;
                d = fabsf(bp[3] - t3); bsum += (d < 1.0f) ? 0.5f * d * d : d - 0.5f;
            }
        }
    }
    __shared__ float s4f[4], s4b[4];
    if (lane == 0) { s4f[threadIdx.x >> 6] = fsum; s4b[threadIdx.x >> 6] = bsum; }
    __syncthreads();
    if (threadIdx.x == 0) {
        atomicAdd(acc + 0, s4f[0] + s4f[1] + s4f[2] + s4f[3]);
        atomicAdd(acc + 1, s4b[0] + s4b[1] + s4b[2] + s4b[3]);
    }
}

// ---------------------------------------------------------------------------
// K6: per-image top-min(npos,128) via MSB-first radix select, then counting-
// sort by matched gt index g. Emits f16 coeffs (RNE cvt), ZERO-PADDED to
// KPOS rows, and sel_g padded with the last (max) g so it stays monotone.
// ---------------------------------------------------------------------------
__global__ __launch_bounds__(1024) void k6_select(
    const unsigned long long* __restrict__ pos_key, const int* __restrict__ pos_cnt,
    const int* __restrict__ gidx, const float* __restrict__ coeffs,
    int* __restrict__ sel_g, _Float16* __restrict__ sel_coef,
    int* __restrict__ sel_cnt) {
    int b = blockIdx.x, tid = threadIdx.x;
    __shared__ unsigned long long s_keys[SELCAP];
    __shared__ int s_hist[256];
    __shared__ int s_sfx[256];
    __shared__ int s_wsum[4];
    __shared__ unsigned long long s_prefix;
    __shared__ int s_kk;
    __shared__ int s_nsel;
    __shared__ int s_sel_a[KPOS];
    __shared__ int s_sorted_a[KPOS];
    __shared__ int s_sorted_g[KPOS];
    __shared__ int s_gcnt[GG];

    int n = pos_cnt[b];
    int K = (n < KPOS) ? n : KPOS;
    const unsigned long long* keys;
    if (n <= SELCAP) {
        for (int i = tid; i < n; i += 1024) s_keys[i] = pos_key[(size_t)b * AA + i];
        keys = s_keys;
    } else {
        keys = pos_key + (size_t)b * AA;
    }
    if (tid == 0) { s_prefix = 0ULL; s_kk = KPOS; s_nsel = 0; }
    __syncthreads();

    if (n > KPOS) {
        for (int d = 6; d >= 0; --d) {
            unsigned long long pref = s_prefix;   // snapshot (post-barrier)
            int kk = s_kk;
            if (tid < 256) s_hist[tid] = 0;
            __syncthreads();
            unsigned long long mhi = ~((1ULL << (8 * (d + 1))) - 1ULL);
            for (int i = tid; i < n; i += 1024) {
                unsigned long long k = keys[i];
                if ((k & mhi) == pref)
                    atomicAdd(&s_hist[(int)((k >> (8 * d)) & 255)], 1);
            }
            __syncthreads();
            int x = 0;
            if (tid < 256) {
                x = s_hist[255 - tid];
                #pragma unroll
                for (int o = 1; o < 64; o <<= 1) {
                    int t = __shfl_up(x, o);
                    if ((tid & 63) >= o) x += t;
                }
                if ((tid & 63) == 63) s_wsum[tid >> 6] = x;
            }
            __syncthreads();
            if (tid == 0) {
                int run = 0;
                #pragma unroll
                for (int i = 0; i < 4; ++i) { int t = s_wsum[i]; s_wsum[i] = run; run += t; }
            }
            __syncthreads();
            if (tid < 256) s_sfx[255 - tid] = x + s_wsum[tid >> 6];
            __syncthreads();
            if (tid < 256) {
                int v = tid;
                int ge = s_sfx[v];
                int gt = (v == 255) ? 0 : s_sfx[v + 1];
                if (ge >= kk && gt < kk) {
                    s_prefix = pref | ((unsigned long long)v << (8 * d));
                    s_kk = kk - gt;
                }
            }
            __syncthreads();
        }
    }

    unsigned long long T = (n > KPOS) ? s_prefix : 0ULL;
    for (int i = tid; i < n; i += 1024) {
        unsigned long long k = keys[i];
        if (k >= T) {
            int slot = atomicAdd(&s_nsel, 1);
            if (slot < KPOS)
                s_sel_a[slot] = AA - 1 - (int)(unsigned)(k & 0xffffffffu);
        }
    }
    __syncthreads();

    if (tid < GG) s_gcnt[tid] = 0;
    __syncthreads();
    int mya = -1, myg = -1;
    if (tid < K) {
        mya = s_sel_a[tid];
        myg = gidx[b * AA + mya];
        atomicAdd(&s_gcnt[myg], 1);
    }
    __syncthreads();
    if (tid == 0) {
        int run = 0;
        for (int g = 0; g < GG; ++g) { int c = s_gcnt[g]; s_gcnt[g] = run; run += c; }
    }
    __syncthreads();
    if (tid < K) {
        int pos = atomicAdd(&s_gcnt[myg], 1);
        s_sorted_a[pos] = mya;
        s_sorted_g[pos] = myg;
    }
    __syncthreads();

    if (tid == 0) sel_cnt[b] = K;
    int glast = (K > 0) ? s_sorted_g[K - 1] : 0;
    for (int t = tid; t < KPOS * PP; t += 1024) {
        int k = t >> 5, p = t & 31;
        _Float16 v = (_Float16)0.0f;
        if (k < K) {
            int a = s_sorted_a[k];
            v = (_Float16)coeffs[((size_t)(b * AA + a)) * PP + p];
        }
        sel_coef[(size_t)(b * KPOS + k) * PP + p] = v;
    }
    for (int t = tid; t < KPOS; t += 1024)
        sel_g[b * KPOS + t] = (t < K) ? s_sorted_g[t] : glast;
}

// ---------------------------------------------------------------------------
// K7 v9: MFMA mask loss consuming the PREPPED operands.
// Per wave: ONE u32 pmask load + ONE contiguous half8 B-frag (the wave's
// 64x16B chunks form a single 1 KB line) + per k-tile {16B A-frag, int4 g,
// MFMA, pure-VALU BCE}. No strided gathers, no f32->f16 cvt, no divergence.
// ---------------------------------------------------------------------------
__global__ __launch_bounds__(256) void k7_mask(
    const _Float16* __restrict__ protoT, const unsigned* __restrict__ pmask,
    const _Float16* __restrict__ sel_coef, const int* __restrict__ sel_g,
    const int* __restrict__ sel_cnt, float* __restrict__ acc_mask) {
    int b = blockIdx.y;
    int nk = sel_cnt[b];
    int tid = threadIdx.x;
    int wave = tid >> 6, lane = tid & 63;
    int lg = lane >> 4;                       // lane group 0..3
    int ln = lane & 15;                       // n (px) / A-row (k) index
    int pt = blockIdx.x * 4 + wave;           // pixel-tile index
    int px = pt * 16 + ln;
    bool pxv = (pt < NPT) && (px < PHW);
    int pc = pxv ? px : PHW - 1;

    // B-frag: protoT[b][pc][lg*8 .. lg*8+8] — 16B contiguous per lane.
    half8 bfrag = *(const half8*)&protoT[((size_t)b * PHW + pc) * PP + lg * 8];
    unsigned gmask = pmask[(size_t)b * PHW + pc];

    const _Float16* ca = sel_coef + (size_t)b * KPOS * PP;
    const int* gb = sel_g + b * KPOS;

    float acc = 0.0f;
    for (int kt = 0; kt < KPOS / 16; ++kt) {
        int k0 = kt * 16;
        if (k0 >= nk) break;                  // uniform (nk per image)
        half8 afrag = *(const half8*)&ca[(size_t)(k0 + ln) * PP + lg * 8];
        int4 gs = *(const int4*)&gb[k0 + lg * 4];
        floatx4 c = {0.f, 0.f, 0.f, 0.f};
        c = __builtin_amdgcn_mfma_f32_16x16x32_f16(afrag, bfrag, c, 0, 0, 0);
        #pragma unroll
        for (int r = 0; r < 4; ++r) {
            int k = k0 + lg * 4 + r;
            float l = c[r];
            int g0 = (r == 0) ? gs.x : (r == 1) ? gs.y : (r == 2) ? gs.z : gs.w;
            float t = (float)((gmask >> g0) & 1u);
            float bce = fmaxf(l, 0.f) - l * t + __logf(1.f + __expf(-fabsf(l)));
            if (pxv && k < nk) acc += bce;
        }
    }

    for (int off = 32; off; off >>= 1) acc += __shfl_xor(acc, off);
    __shared__ float s_red[4];
    if (lane == 0) s_red[wave] = acc;
    __syncthreads();
    if (tid == 0)
        atomicAdd(acc_mask, s_red[0] + s_red[1] + s_red[2] + s_red[3]);
}

// ---------------------------------------------------------------------------
// K8: finalize.
// ---------------------------------------------------------------------------
__global__ void k8_final(const float* __restrict__ acc, const int* __restrict__ npos,
                         float* __restrict__ out) {
    float denom = fmaxf((float)(*npos), 1.0f);
    out[0] = (1.0f * acc[0] + 1.5f * acc[1] + 6.125f * (acc[2] / (float)PHW)) / denom;
}

// ---------------------------------------------------------------------------
extern "C" void kernel_launch(void* const* d_in, const int* in_sizes, int n_in,
                              void* d_out, int out_size, void* d_ws, size_t ws_size,
                              hipStream_t stream) {
    (void)in_sizes; (void)n_in; (void)out_size; (void)ws_size;
    const float* class_preds = (const float*)d_in[0];
    const float* box_preds   = (const float*)d_in[1];
    const float* mask_coeffs = (const float*)d_in[2];
    const float* prototypes  = (const float*)d_in[3];
    const float* anchors     = (const float*)d_in[4];
    const float* gt_boxes    = (const float*)d_in[5];
    const int*   gt_labels   = (const int*)d_in[6];
    const float* gt_masks    = (const float*)d_in[7];
    float* out = (float*)d_out;

    size_t off = 0;
    char* w = (char*)d_ws;
    auto take = [&](size_t bytes) -> char* {
        char* p = w + off;
        off += (bytes + 255) & ~(size_t)255;
        return p;
    };
    float* acc      = (float*)take(32);                       // [cls, box, mask, npos(int)]
    float* best_iou = (float*)take((size_t)BB * AA * 4);
    int*   best_g   = (int*)  take((size_t)BB * AA * 4);
    int*   gidx     = (int*)  take((size_t)BB * AA * 4);
    int*   selmask  = (int*)  take((size_t)BB * AA * 4);
    unsigned long long* gkey_part =
        (unsigned long long*)take((size_t)BB * NB1 * GG * 8);
    int*   pos_cnt  = (int*)  take((size_t)BB * 4);
    unsigned long long* pos_key = (unsigned long long*)take((size_t)BB * AA * 8);
    int*   sel_g    = (int*)  take((size_t)BB * KPOS * 4);
    int*   sel_cnt  = (int*)  take((size_t)BB * 4);
    _Float16* sel_coef = (_Float16*)take((size_t)BB * KPOS * PP * 2);
    int*   act_list = (int*)  take((size_t)BB * AA * 4);
    int*   act_cnt  = (int*)  take((size_t)BB * 4);
    _Float16* protoT = (_Float16*)take((size_t)BB * PHW * PP * 2);
    unsigned* pmaskb = (unsigned*)take((size_t)BB * PHW * 4);

    k0_prep<<<dim3((PHW + 255) / 256, BB), 256, 0, stream>>>(
        prototypes, gt_masks, protoT, pmaskb);
    k1_match<<<dim3(NB1, BB), 256, 0, stream>>>(
        anchors, gt_boxes, best_iou, best_g, gkey_part, acc);
    k3_match_scan<<<BB, 1024, 0, stream>>>(
        best_iou, best_g, gkey_part, gidx, selmask, pos_key, pos_cnt, (int*)(acc + 3),
        act_list, act_cnt);
    k45_cls_box<<<dim3(K45BLK, BB), 256, 0, stream>>>(
        class_preds, gt_labels, gidx, selmask, act_list, act_cnt,
        box_preds, anchors, gt_boxes, acc);
    k6_select<<<BB, 1024, 0, stream>>>(
        pos_key, pos_cnt, gidx, mask_coeffs, sel_g, sel_coef, sel_cnt);
    k7_mask<<<dim3(NB7, BB), 256, 0, stream>>>(
        protoT, pmaskb, sel_coef, sel_g, sel_cnt, acc + 2);
    k8_final<<<1, 1, 0, stream>>>(acc, (int*)(acc + 3), out);
}

// Round 14
// 106.063 us; speedup vs baseline: 1.2256x; 1.2256x over previous
//
#include <hip/hip_runtime.h>
#include <math.h>

#define BB 8
#define AA 19248
#define GG 32
#define CC 81
#define PP 32
#define PHW 19044   /* 138*138 */
#define KPOS 128
#define NEGRATIO 3
#define SELCAP 7680
#define NWCH 304    /* 19 outer iters x 16 waves of 64 anchors */
#define NB1 76      /* k1 blocks per image = ceil(AA/256) */
#define NPT 1191    /* pixel tiles of 16 = ceil(PHW/16) */
#define NB7 298     /* k7 blocks per image = ceil(NPT/4) */
#define NB45 32     /* k45 blocks per image */

typedef _Float16 half8 __attribute__((ext_vector_type(8)));
typedef float floatx4 __attribute__((ext_vector_type(4)));

// ---------------------------------------------------------------------------
// IoU helper — contraction off so every recomputation produces bitwise-
// identical values and FMA fusion can't flip threshold/argmax decisions.
// ---------------------------------------------------------------------------
__device__ __forceinline__ float iou_one(float ax1, float ay1, float ax2, float ay2,
                                         float areaA,
                                         float gx1, float gy1, float gx2, float gy2) {
#pragma clang fp contract(off)
    float ix1 = fmaxf(ax1, gx1), iy1 = fmaxf(ay1, gy1);
    float ix2 = fminf(ax2, gx2), iy2 = fminf(ay2, gy2);
    float iw = fmaxf(ix2 - ix1, 0.0f), ih = fmaxf(iy2 - iy1, 0.0f);
    float inter = iw * ih;
    float areaB = (gx2 - gx1) * (gy2 - gy1);
    float u = areaA + areaB - inter;
    u = fmaxf(u, 1e-6f);
    return inter / u;
}

// ---------------------------------------------------------------------------
// K0: streaming prep — per pixel, (a) pack the 32 binary gt-masks into one
// u32, (b) transpose protos to [b][px][32] f16 (RNE). Coalesced both ways.
// ---------------------------------------------------------------------------
__global__ __launch_bounds__(256) void k0_prep(
    const float* __restrict__ protos, const float* __restrict__ gtm,
    _Float16* __restrict__ protoT, unsigned* __restrict__ pmask) {
    int b = blockIdx.y;
    int px = blockIdx.x * 256 + threadIdx.x;
    if (px >= PHW) return;
    const float* pb = protos + (size_t)b * PP * PHW + px;
    _Float16 v[PP];
    #pragma unroll
    for (int k = 0; k < PP; ++k)
        v[k] = (_Float16)pb[(size_t)k * PHW];
    half8* dst = (half8*)&protoT[((size_t)b * PHW + px) * PP];
    #pragma unroll
    for (int q = 0; q < 4; ++q)
        dst[q] = *(half8*)&v[q * 8];
    const float* gb = gtm + (size_t)b * GG * PHW + px;
    unsigned m = 0u;
    #pragma unroll
    for (int g = 0; g < GG; ++g)
        m |= (gb[(size_t)g * PHW] > 0.5f) ? (1u << g) : 0u;
    pmask[(size_t)b * PHW + px] = m;
}

// ---------------------------------------------------------------------------
// K1: per (b,a) best IoU + first-max argmax over g, AND per-(b,g) best-anchor
// partial keys per block (value desc, index asc), reduced in K3.
// ---------------------------------------------------------------------------
__global__ __launch_bounds__(256) void k1_match(
    const float* __restrict__ anchors, const float* __restrict__ gt_boxes,
    float* __restrict__ best_iou, int* __restrict__ best_g,
    unsigned long long* __restrict__ gkey_part, float* __restrict__ acc) {
#pragma clang fp contract(off)
    int b = blockIdx.y;
    int a = blockIdx.x * 256 + threadIdx.x;
    int lane = threadIdx.x & 63;
    if (blockIdx.x == 0 && b == 0 && threadIdx.x < 4)
        ((int*)acc)[threadIdx.x] = 0;            // zero [cls, box, mask, npos]
    __shared__ float sg[GG][4];
    __shared__ unsigned long long s_gk[GG];
    for (int t = threadIdx.x; t < GG * 4; t += 256)
        sg[t >> 2][t & 3] = gt_boxes[b * GG * 4 + t] / 550.0f;
    if (threadIdx.x < GG) s_gk[threadIdx.x] = 0ULL;
    __syncthreads();
    bool valid = a < AA;
    int ac = valid ? a : AA - 1;
    float4 an = ((const float4*)anchors)[ac];
    float ax1 = an.x - an.z * 0.5f, ay1 = an.y - an.w * 0.5f;
    float ax2 = an.x + an.z * 0.5f, ay2 = an.y + an.w * 0.5f;
    float areaA = (ax2 - ax1) * (ay2 - ay1);
    unsigned long long bk = 0ULL;   // (vbits<<6)|(31-g): max => first-max argmax
    for (int gg = 0; gg < GG; ++gg) {
        int g = (gg + lane) & (GG - 1);          // stagger: 32 distinct LDS slots
        float v = iou_one(ax1, ay1, ax2, ay2, areaA, sg[g][0], sg[g][1], sg[g][2], sg[g][3]);
        unsigned vb = __float_as_uint(v);        // v >= 0 -> order-preserving
        unsigned long long k2 = ((unsigned long long)vb << 6) | (unsigned)(GG - 1 - g);
        if (k2 > bk) bk = k2;
        if (valid) {
            unsigned long long kg =
                ((unsigned long long)vb << 32) | (unsigned)(AA - 1 - a);
            atomicMax(&s_gk[g], kg);
        }
    }
    if (valid) {
        best_iou[b * AA + a] = __uint_as_float((unsigned)(bk >> 6));
        best_g[b * AA + a] = (GG - 1) - (int)(bk & 63ULL);
    }
    __syncthreads();
    if (threadIdx.x < GG)
        gkey_part[((size_t)b * NB1 + blockIdx.x) * GG + threadIdx.x] = s_gk[threadIdx.x];
}

// ---------------------------------------------------------------------------
// K3: per image — reduce per-block gt keys, scatter overrides via an O(1) LDS
// lookup table (ascending g -> last wins, matching XLA scatter), pos
// compaction + keys, hard-negative cap via ballot-based scan, active-row
// compaction. act_list entries are PACKED: a(15b) | g(5b)<<15 | lbl(7b)<<20 |
// pos<<31 — K45 then needs no selmask/gidx/gtl pointer chase.
// ---------------------------------------------------------------------------
__global__ __launch_bounds__(1024) void k3_match_scan(
    const float* __restrict__ best_iou, const int* __restrict__ best_g_in,
    const unsigned long long* __restrict__ gkey_part, const int* __restrict__ gtl,
    int* __restrict__ gidx_out, int* __restrict__ selmask,
    unsigned long long* __restrict__ pos_key,
    int* __restrict__ pos_cnt, int* __restrict__ g_npos,
    int* __restrict__ act_list, int* __restrict__ act_cnt) {
#pragma clang fp contract(off)
    int b = blockIdx.x;
    int tid = threadIdx.x;
    int lane = tid & 63, wid = tid >> 6;
    __shared__ short s_ov[AA];                  // override g per anchor, -1 none
    __shared__ unsigned long long s_gmax[GG];
    __shared__ int sba[GG];
    __shared__ int s_gtl[GG];
    __shared__ unsigned long long s_pmask[NWCH];
    __shared__ unsigned long long s_nmask[NWCH];
    __shared__ int s_woff[NWCH];
    __shared__ int s_wred[5];
    __shared__ int s_cnt, s_act;
    for (int i = tid; i < AA; i += 1024) s_ov[i] = -1;
    if (tid < GG) { s_gmax[tid] = 0ULL; s_gtl[tid] = gtl[b * GG + tid]; }
    if (tid == 0) { s_cnt = 0; s_act = 0; }
    __syncthreads();
    // reduce 76 per-block partial keys per g (32 g x 32 groups)
    for (int c = tid >> 5; c < NB1; c += 32)
        atomicMax(&s_gmax[tid & 31],
                  gkey_part[((size_t)b * NB1 + c) * GG + (tid & 31)]);
    __syncthreads();
    if (tid < GG) sba[tid] = AA - 1 - (int)(unsigned)(s_gmax[tid] & 0xffffffffULL);
    __syncthreads();
    if (tid == 0) {
        for (int g = 0; g < GG; ++g) s_ov[sba[g]] = (short)g;  // ascending: last wins
    }
    __syncthreads();

    // pass 1: matching decisions + pos keys + per-wave-chunk ballots
    for (int base = 0; base < AA; base += 1024) {
        int a = base + tid;
        bool p = false, npre = false;
        if (a < AA) {
            float biou = best_iou[b * AA + a];
            int ov = s_ov[a];
            int gi = (ov >= 0) ? ov : best_g_in[b * AA + a];
            p = (biou >= 0.5f) || (ov >= 0);
            npre = (biou < 0.4f) && !p;
            gidx_out[b * AA + a] = gi;
            selmask[b * AA + a] = p ? 2 : (npre ? 1 : 0);
            if (p) {
                int slot = atomicAdd(&s_cnt, 1);
                unsigned vb = __float_as_uint(biou + 1.0f);   // >= 0x3F800000
                unsigned long long key =
                    ((unsigned long long)(vb - 0x3F800000u) << 32) |
                    (unsigned)(AA - 1 - a);
                pos_key[(size_t)b * AA + slot] = key;
            }
        }
        unsigned long long pm = __ballot(p);
        unsigned long long nm = __ballot(npre);
        if (lane == 0) {
            int w = (base >> 6) + wid;
            s_pmask[w] = pm;
            s_nmask[w] = nm;
        }
    }
    __syncthreads();
    int npos = s_cnt;
    if (tid == 0) { pos_cnt[b] = npos; atomicAdd(g_npos, npos); }
    int cap = npos * NEGRATIO;

    // scan 304 chunk counts with 5 waves
    int c = (tid < NWCH) ? __popcll(s_nmask[tid]) : 0;
    int inc = c;
    if (wid < 5) {
        #pragma unroll
        for (int d = 1; d < 64; d <<= 1) {
            int t = __shfl_up(inc, d);
            if (lane >= d) inc += t;
        }
        if (lane == 63) s_wred[wid] = inc;
    }
    __syncthreads();
    if (tid == 0) {
        int run = 0;
        #pragma unroll
        for (int i = 0; i < 5; ++i) { int t = s_wred[i]; s_wred[i] = run; run += t; }
    }
    __syncthreads();
    if (tid < NWCH) s_woff[tid] = inc - c + s_wred[wid];   // exclusive prefix
    __syncthreads();

    // pass 2: drop negs beyond cap, compact PACKED active rows (order-free)
    for (int base = 0; base < AA; base += 1024) {
        int a = base + tid;
        int w = (base >> 6) + wid;
        unsigned long long nm = s_nmask[w], pm = s_pmask[w];
        bool npre = (nm >> lane) & 1ULL;
        bool pos  = (pm >> lane) & 1ULL;
        int rank = __popcll(nm & ((1ULL << lane) - 1ULL));
        bool kept = npre && (s_woff[w] + rank + 1 <= cap);
        if (a < AA) {
            if (npre && !kept) selmask[b * AA + a] = 0;
            if (pos || kept) {
                int slot = atomicAdd(&s_act, 1);
                int gi = gidx_out[b * AA + a];          // same-block write, L1
                int lbl = pos ? s_gtl[gi] : 0;
                unsigned e = (unsigned)a | ((unsigned)gi << 15) |
                             ((unsigned)lbl << 20) | (pos ? 0x80000000u : 0u);
                act_list[b * AA + slot] = (int)e;
            }
        }
    }
    __syncthreads();
    if (tid == 0) act_cnt[b] = s_act;
}

// ---------------------------------------------------------------------------
// K45 v2: focal + box loss, THREAD-PER-ROW (round-13 top cost was a wave-per-
// row design: 12 dependent shuffles + a 4-deep lane-0 pointer chase per row,
// 41 us at 13% VALUBusy). Per thread: packed act entry (1 load) -> 81
// independent scalar loads (4 parallel max chains), second L1-hot pass for
// sum-exp (64 rows/wave = 24 KB fits L1), focal on every lane. Box loss via
// three float4 loads for pos rows. One wave+block reduction at the end.
// ---------------------------------------------------------------------------
__global__ __launch_bounds__(256) void k45_cls_box(
    const float* __restrict__ cls_p, const int* __restrict__ act_list,
    const int* __restrict__ act_cnt, const float* __restrict__ box_p,
    const float* __restrict__ anchors, const float* __restrict__ gt_boxes,
    float* __restrict__ acc) {
    int b = blockIdx.y;
    int n = act_cnt[b];
    float fsum = 0.0f, bsum = 0.0f;
    for (int i = blockIdx.x * 256 + threadIdx.x; i < n; i += NB45 * 256) {
        unsigned e = (unsigned)act_list[b * AA + i];
        int a = e & 0x7fff;
        int g = (e >> 15) & 31;
        int lbl = (e >> 20) & 127;
        bool pos = (e >> 31) != 0u;
        const float* x = cls_p + (size_t)(b * AA + a) * CC;
        float v80 = x[80];
        float m0 = v80, m1 = -3.0e38f, m2 = -3.0e38f, m3 = -3.0e38f;
        #pragma unroll
        for (int q = 0; q < 20; ++q) {
            m0 = fmaxf(m0, x[4 * q + 0]); m1 = fmaxf(m1, x[4 * q + 1]);
            m2 = fmaxf(m2, x[4 * q + 2]); m3 = fmaxf(m3, x[4 * q + 3]);
        }
        float m = fmaxf(fmaxf(m0, m1), fmaxf(m2, m3));
        float s0 = __expf(v80 - m), s1 = 0.f, s2 = 0.f, s3 = 0.f;
        #pragma unroll
        for (int q = 0; q < 20; ++q) {
            s0 += __expf(x[4 * q + 0] - m); s1 += __expf(x[4 * q + 1] - m);
            s2 += __expf(x[4 * q + 2] - m); s3 += __expf(x[4 * q + 3] - m);
        }
        float s = (s0 + s1) + (s2 + s3);
        float pt = __expf(x[lbl] - m) / s;
        pt = fminf(fmaxf(pt, 1e-6f), 1.0f - 1e-6f);
        float at = (lbl > 0) ? 0.25f : 0.75f;
        float om = 1.0f - pt;
        fsum += at * om * om * (-__logf(pt));
        if (pos) {
#pragma clang fp contract(off)
            float4 mb = ((const float4*)gt_boxes)[b * GG + g];
            float4 an = ((const float4*)anchors)[a];
            const float4 bp = ((const float4*)box_p)[(size_t)b * AA + a];
            float q0 = mb.x / 550.0f, q1 = mb.y / 550.0f;
            float q2 = mb.z / 550.0f, q3 = mb.w / 550.0f;
            float gcx = 0.5f * (q0 + q2), gcy = 0.5f * (q1 + q3);
            float gw = fmaxf(q2 - q0, 1e-6f), gh = fmaxf(q3 - q1, 1e-6f);
            float t0 = (gcx - an.x) / (an.z * 0.1f);
            float t1 = (gcy - an.y) / (an.w * 0.1f);
            float t2 = logf(gw / an.z) / 0.2f;
            float t3 = logf(gh / an.w) / 0.2f;
            float d;
            d = fabsf(bp.x - t0); bsum += (d < 1.0f) ? 0.5f * d * d : d - 0.5f;
            d = fabsf(bp.y - t1); bsum += (d < 1.0f) ? 0.5f * d * d : d - 0.5f;
            d = fabsf(bp.z - t2); bsum += (d < 1.0f) ? 0.5f * d * d : d - 0.5f;
            d = fabsf(bp.w - t3); bsum += (d < 1.0f) ? 0.5f * d * d : d - 0.5f;
        }
    }
    for (int off = 32; off; off >>= 1) {
        fsum += __shfl_xor(fsum, off);
        bsum += __shfl_xor(bsum, off);
    }
    __shared__ float s4f[4], s4b[4];
    if ((threadIdx.x & 63) == 0) {
        s4f[threadIdx.x >> 6] = fsum;
        s4b[threadIdx.x >> 6] = bsum;
    }
    __syncthreads();
    if (threadIdx.x == 0) {
        atomicAdd(acc + 0, s4f[0] + s4f[1] + s4f[2] + s4f[3]);
        atomicAdd(acc + 1, s4b[0] + s4b[1] + s4b[2] + s4b[3]);
    }
}

// ---------------------------------------------------------------------------
// K6: per-image top-min(npos,128) via MSB-first radix select, then counting-
// sort by matched gt index g. Emits f16 coeffs (RNE cvt), ZERO-PADDED to
// KPOS rows, and sel_g padded with the last (max) g so it stays monotone.
// ---------------------------------------------------------------------------
__global__ __launch_bounds__(1024) void k6_select(
    const unsigned long long* __restrict__ pos_key, const int* __restrict__ pos_cnt,
    const int* __restrict__ gidx, const float* __restrict__ coeffs,
    int* __restrict__ sel_g, _Float16* __restrict__ sel_coef,
    int* __restrict__ sel_cnt) {
    int b = blockIdx.x, tid = threadIdx.x;
    __shared__ unsigned long long s_keys[SELCAP];
    __shared__ int s_hist[256];
    __shared__ int s_sfx[256];
    __shared__ int s_wsum[4];
    __shared__ unsigned long long s_prefix;
    __shared__ int s_kk;
    __shared__ int s_nsel;
    __shared__ int s_sel_a[KPOS];
    __shared__ int s_sorted_a[KPOS];
    __shared__ int s_sorted_g[KPOS];
    __shared__ int s_gcnt[GG];

    int n = pos_cnt[b];
    int K = (n < KPOS) ? n : KPOS;
    const unsigned long long* keys;
    if (n <= SELCAP) {
        for (int i = tid; i < n; i += 1024) s_keys[i] = pos_key[(size_t)b * AA + i];
        keys = s_keys;
    } else {
        keys = pos_key + (size_t)b * AA;
    }
    if (tid == 0) { s_prefix = 0ULL; s_kk = KPOS; s_nsel = 0; }
    __syncthreads();

    if (n > KPOS) {
        for (int d = 6; d >= 0; --d) {
            unsigned long long pref = s_prefix;   // snapshot (post-barrier)
            int kk = s_kk;
            if (tid < 256) s_hist[tid] = 0;
            __syncthreads();
            unsigned long long mhi = ~((1ULL << (8 * (d + 1))) - 1ULL);
            for (int i = tid; i < n; i += 1024) {
                unsigned long long k = keys[i];
                if ((k & mhi) == pref)
                    atomicAdd(&s_hist[(int)((k >> (8 * d)) & 255)], 1);
            }
            __syncthreads();
            int x = 0;
            if (tid < 256) {
                x = s_hist[255 - tid];
                #pragma unroll
                for (int o = 1; o < 64; o <<= 1) {
                    int t = __shfl_up(x, o);
                    if ((tid & 63) >= o) x += t;
                }
                if ((tid & 63) == 63) s_wsum[tid >> 6] = x;
            }
            __syncthreads();
            if (tid == 0) {
                int run = 0;
                #pragma unroll
                for (int i = 0; i < 4; ++i) { int t = s_wsum[i]; s_wsum[i] = run; run += t; }
            }
            __syncthreads();
            if (tid < 256) s_sfx[255 - tid] = x + s_wsum[tid >> 6];
            __syncthreads();
            if (tid < 256) {
                int v = tid;
                int ge = s_sfx[v];
                int gt = (v == 255) ? 0 : s_sfx[v + 1];
                if (ge >= kk && gt < kk) {
                    s_prefix = pref | ((unsigned long long)v << (8 * d));
                    s_kk = kk - gt;
                }
            }
            __syncthreads();
        }
    }

    unsigned long long T = (n > KPOS) ? s_prefix : 0ULL;
    for (int i = tid; i < n; i += 1024) {
        unsigned long long k = keys[i];
        if (k >= T) {
            int slot = atomicAdd(&s_nsel, 1);
            if (slot < KPOS)
                s_sel_a[slot] = AA - 1 - (int)(unsigned)(k & 0xffffffffu);
        }
    }
    __syncthreads();

    if (tid < GG) s_gcnt[tid] = 0;
    __syncthreads();
    int mya = -1, myg = -1;
    if (tid < K) {
        mya = s_sel_a[tid];
        myg = gidx[b * AA + mya];
        atomicAdd(&s_gcnt[myg], 1);
    }
    __syncthreads();
    if (tid == 0) {
        int run = 0;
        for (int g = 0; g < GG; ++g) { int c = s_gcnt[g]; s_gcnt[g] = run; run += c; }
    }
    __syncthreads();
    if (tid < K) {
        int pos = atomicAdd(&s_gcnt[myg], 1);
        s_sorted_a[pos] = mya;
        s_sorted_g[pos] = myg;
    }
    __syncthreads();

    if (tid == 0) sel_cnt[b] = K;
    int glast = (K > 0) ? s_sorted_g[K - 1] : 0;
    for (int t = tid; t < KPOS * PP; t += 1024) {
        int k = t >> 5, p = t & 31;
        _Float16 v = (_Float16)0.0f;
        if (k < K) {
            int a = s_sorted_a[k];
            v = (_Float16)coeffs[((size_t)(b * AA + a)) * PP + p];
        }
        sel_coef[(size_t)(b * KPOS + k) * PP + p] = v;
    }
    for (int t = tid; t < KPOS; t += 1024)
        sel_g[b * KPOS + t] = (t < K) ? s_sorted_g[t] : glast;
}

// ---------------------------------------------------------------------------
// K7 v9: MFMA mask loss consuming the PREPPED operands.
// Per wave: ONE u32 pmask load + ONE contiguous half8 B-frag + per k-tile
// {16B A-frag, int4 g, MFMA, pure-VALU BCE}. No strided gathers, no cvt.
// ---------------------------------------------------------------------------
__global__ __launch_bounds__(256) void k7_mask(
    const _Float16* __restrict__ protoT, const unsigned* __restrict__ pmask,
    const _Float16* __restrict__ sel_coef, const int* __restrict__ sel_g,
    const int* __restrict__ sel_cnt, float* __restrict__ acc_mask) {
    int b = blockIdx.y;
    int nk = sel_cnt[b];
    int tid = threadIdx.x;
    int wave = tid >> 6, lane = tid & 63;
    int lg = lane >> 4;                       // lane group 0..3
    int ln = lane & 15;                       // n (px) / A-row (k) index
    int pt = blockIdx.x * 4 + wave;           // pixel-tile index
    int px = pt * 16 + ln;
    bool pxv = (pt < NPT) && (px < PHW);
    int pc = pxv ? px : PHW - 1;

    half8 bfrag = *(const half8*)&protoT[((size_t)b * PHW + pc) * PP + lg * 8];
    unsigned gmask = pmask[(size_t)b * PHW + pc];

    const _Float16* ca = sel_coef + (size_t)b * KPOS * PP;
    const int* gb = sel_g + b * KPOS;

    float acc = 0.0f;
    for (int kt = 0; kt < KPOS / 16; ++kt) {
        int k0 = kt * 16;
        if (k0 >= nk) break;                  // uniform (nk per image)
        half8 afrag = *(const half8*)&ca[(size_t)(k0 + ln) * PP + lg * 8];
        int4 gs = *(const int4*)&gb[k0 + lg * 4];
        floatx4 c = {0.f, 0.f, 0.f, 0.f};
        c = __builtin_amdgcn_mfma_f32_16x16x32_f16(afrag, bfrag, c, 0, 0, 0);
        #pragma unroll
        for (int r = 0; r < 4; ++r) {
            int k = k0 + lg * 4 + r;
            float l = c[r];
            int g0 = (r == 0) ? gs.x : (r == 1) ? gs.y : (r == 2) ? gs.z : gs.w;
            float t = (float)((gmask >> g0) & 1u);
            float bce = fmaxf(l, 0.f) - l * t + __logf(1.f + __expf(-fabsf(l)));
            if (pxv && k < nk) acc += bce;
        }
    }

    for (int off = 32; off; off >>= 1) acc += __shfl_xor(acc, off);
    __shared__ float s_red[4];
    if (lane == 0) s_red[wave] = acc;
    __syncthreads();
    if (tid == 0)
        atomicAdd(acc_mask, s_red[0] + s_red[1] + s_red[2] + s_red[3]);
}

// ---------------------------------------------------------------------------
// K8: finalize.
// ---------------------------------------------------------------------------
__global__ void k8_final(const float* __restrict__ acc, const int* __restrict__ npos,
                         float* __restrict__ out) {
    float denom = fmaxf((float)(*npos), 1.0f);
    out[0] = (1.0f * acc[0] + 1.5f * acc[1] + 6.125f * (acc[2] / (float)PHW)) / denom;
}

// ---------------------------------------------------------------------------
extern "C" void kernel_launch(void* const* d_in, const int* in_sizes, int n_in,
                              void* d_out, int out_size, void* d_ws, size_t ws_size,
                              hipStream_t stream) {
    (void)in_sizes; (void)n_in; (void)out_size; (void)ws_size;
    const float* class_preds = (const float*)d_in[0];
    const float* box_preds   = (const float*)d_in[1];
    const float* mask_coeffs = (const float*)d_in[2];
    const float* prototypes  = (const float*)d_in[3];
    const float* anchors     = (const float*)d_in[4];
    const float* gt_boxes    = (const float*)d_in[5];
    const int*   gt_labels   = (const int*)d_in[6];
    const float* gt_masks    = (const float*)d_in[7];
    float* out = (float*)d_out;

    size_t off = 0;
    char* w = (char*)d_ws;
    auto take = [&](size_t bytes) -> char* {
        char* p = w + off;
        off += (bytes + 255) & ~(size_t)255;
        return p;
    };
    float* acc      = (float*)take(32);                       // [cls, box, mask, npos(int)]
    float* best_iou = (float*)take((size_t)BB * AA * 4);
    int*   best_g   = (int*)  take((size_t)BB * AA * 4);
    int*   gidx     = (int*)  take((size_t)BB * AA * 4);
    int*   selmask  = (int*)  take((size_t)BB * AA * 4);
    unsigned long long* gkey_part =
        (unsigned long long*)take((size_t)BB * NB1 * GG * 8);
    int*   pos_cnt  = (int*)  take((size_t)BB * 4);
    unsigned long long* pos_key = (unsigned long long*)take((size_t)BB * AA * 8);
    int*   sel_g    = (int*)  take((size_t)BB * KPOS * 4);
    int*   sel_cnt  = (int*)  take((size_t)BB * 4);
    _Float16* sel_coef = (_Float16*)take((size_t)BB * KPOS * PP * 2);
    int*   act_list = (int*)  take((size_t)BB * AA * 4);
    int*   act_cnt  = (int*)  take((size_t)BB * 4);
    _Float16* protoT = (_Float16*)take((size_t)BB * PHW * PP * 2);
    unsigned* pmaskb = (unsigned*)take((size_t)BB * PHW * 4);

    k0_prep<<<dim3((PHW + 255) / 256, BB), 256, 0, stream>>>(
        prototypes, gt_masks, protoT, pmaskb);
    k1_match<<<dim3(NB1, BB), 256, 0, stream>>>(
        anchors, gt_boxes, best_iou, best_g, gkey_part, acc);
    k3_match_scan<<<BB, 1024, 0, stream>>>(
        best_iou, best_g, gkey_part, gt_labels, gidx, selmask, pos_key, pos_cnt,
        (int*)(acc + 3), act_list, act_cnt);
    k45_cls_box<<<dim3(NB45, BB), 256, 0, stream>>>(
        class_preds, act_list, act_cnt, box_preds, anchors, gt_boxes, acc);
    k6_select<<<BB, 1024, 0, stream>>>(
        pos_key, pos_cnt, gidx, mask_coeffs, sel_g, sel_coef, sel_cnt);
    k7_mask<<<dim3(NB7, BB), 256, 0, stream>>>(
        protoT, pmaskb, sel_coef, sel_g, sel_cnt, acc + 2);
    k8_final<<<1, 1, 0, stream>>>(acc, (int*)(acc + 3), out);
}

// Round 15
// 84.084 us; speedup vs baseline: 1.5460x; 1.2614x over previous
//
#include <hip/hip_runtime.h>
#include <math.h>

#define BB 8
#define AA 19248
#define GG 32
#define CC 81
#define PP 32
#define PHW 19044   /* 138*138 */
#define KPOS 128
#define NEGRATIO 3
#define SELCAP 7680
#define NWCH 304    /* 19 outer iters x 16 waves of 64 anchors */
#define NB1 76      /* k1 blocks per image = ceil(AA/256) */
#define NPT 1191    /* pixel tiles of 16 = ceil(PHW/16) */
#define NB7 298     /* k7 blocks per image = ceil(NPT/4) */
#define NB45 32     /* k45 blocks per image */

typedef _Float16 half8 __attribute__((ext_vector_type(8)));
typedef float floatx4 __attribute__((ext_vector_type(4)));

// ---------------------------------------------------------------------------
// IoU helper — contraction off so every recomputation produces bitwise-
// identical values and FMA fusion can't flip threshold/argmax decisions.
// ---------------------------------------------------------------------------
__device__ __forceinline__ float iou_one(float ax1, float ay1, float ax2, float ay2,
                                         float areaA,
                                         float gx1, float gy1, float gx2, float gy2) {
#pragma clang fp contract(off)
    float ix1 = fmaxf(ax1, gx1), iy1 = fmaxf(ay1, gy1);
    float ix2 = fminf(ax2, gx2), iy2 = fminf(ay2, gy2);
    float iw = fmaxf(ix2 - ix1, 0.0f), ih = fmaxf(iy2 - iy1, 0.0f);
    float inter = iw * ih;
    float areaB = (gx2 - gx1) * (gy2 - gy1);
    float u = areaA + areaB - inter;
    u = fmaxf(u, 1e-6f);
    return inter / u;
}

// ---------------------------------------------------------------------------
// K0: streaming prep — per pixel, (a) pack the 32 binary gt-masks into one
// u32, (b) transpose protos to [b][px][32] f16 (RNE). Coalesced both ways.
// ---------------------------------------------------------------------------
__global__ __launch_bounds__(256) void k0_prep(
    const float* __restrict__ protos, const float* __restrict__ gtm,
    _Float16* __restrict__ protoT, unsigned* __restrict__ pmask) {
    int b = blockIdx.y;
    int px = blockIdx.x * 256 + threadIdx.x;
    if (px >= PHW) return;
    const float* pb = protos + (size_t)b * PP * PHW + px;
    _Float16 v[PP];
    #pragma unroll
    for (int k = 0; k < PP; ++k)
        v[k] = (_Float16)pb[(size_t)k * PHW];
    half8* dst = (half8*)&protoT[((size_t)b * PHW + px) * PP];
    #pragma unroll
    for (int q = 0; q < 4; ++q)
        dst[q] = *(half8*)&v[q * 8];
    const float* gb = gtm + (size_t)b * GG * PHW + px;
    unsigned m = 0u;
    #pragma unroll
    for (int g = 0; g < GG; ++g)
        m |= (gb[(size_t)g * PHW] > 0.5f) ? (1u << g) : 0u;
    pmask[(size_t)b * PHW + px] = m;
}

// ---------------------------------------------------------------------------
// K1: per (b,a) best IoU + first-max argmax over g, AND per-(b,g) best-anchor
// partial keys per block (value desc, index asc), reduced in K3.
// ---------------------------------------------------------------------------
__global__ __launch_bounds__(256) void k1_match(
    const float* __restrict__ anchors, const float* __restrict__ gt_boxes,
    float* __restrict__ best_iou, int* __restrict__ best_g,
    unsigned long long* __restrict__ gkey_part, float* __restrict__ acc) {
#pragma clang fp contract(off)
    int b = blockIdx.y;
    int a = blockIdx.x * 256 + threadIdx.x;
    int lane = threadIdx.x & 63;
    if (blockIdx.x == 0 && b == 0 && threadIdx.x < 4)
        ((int*)acc)[threadIdx.x] = 0;            // zero [cls, box, mask, npos]
    __shared__ float sg[GG][4];
    __shared__ unsigned long long s_gk[GG];
    for (int t = threadIdx.x; t < GG * 4; t += 256)
        sg[t >> 2][t & 3] = gt_boxes[b * GG * 4 + t] / 550.0f;
    if (threadIdx.x < GG) s_gk[threadIdx.x] = 0ULL;
    __syncthreads();
    bool valid = a < AA;
    int ac = valid ? a : AA - 1;
    float4 an = ((const float4*)anchors)[ac];
    float ax1 = an.x - an.z * 0.5f, ay1 = an.y - an.w * 0.5f;
    float ax2 = an.x + an.z * 0.5f, ay2 = an.y + an.w * 0.5f;
    float areaA = (ax2 - ax1) * (ay2 - ay1);
    unsigned long long bk = 0ULL;   // (vbits<<6)|(31-g): max => first-max argmax
    for (int gg = 0; gg < GG; ++gg) {
        int g = (gg + lane) & (GG - 1);          // stagger: 32 distinct LDS slots
        float v = iou_one(ax1, ay1, ax2, ay2, areaA, sg[g][0], sg[g][1], sg[g][2], sg[g][3]);
        unsigned vb = __float_as_uint(v);        // v >= 0 -> order-preserving
        unsigned long long k2 = ((unsigned long long)vb << 6) | (unsigned)(GG - 1 - g);
        if (k2 > bk) bk = k2;
        if (valid) {
            unsigned long long kg =
                ((unsigned long long)vb << 32) | (unsigned)(AA - 1 - a);
            atomicMax(&s_gk[g], kg);
        }
    }
    if (valid) {
        best_iou[b * AA + a] = __uint_as_float((unsigned)(bk >> 6));
        best_g[b * AA + a] = (GG - 1) - (int)(bk & 63ULL);
    }
    __syncthreads();
    if (threadIdx.x < GG)
        gkey_part[((size_t)b * NB1 + blockIdx.x) * GG + threadIdx.x] = s_gk[threadIdx.x];
}

// ---------------------------------------------------------------------------
// K3: per image — reduce per-block gt keys, scatter overrides via an O(1) LDS
// lookup table (ascending g -> last wins, matching XLA scatter), pos
// compaction + keys, hard-negative cap via ballot-based scan, active-row
// compaction. act_list entries are PACKED: a(15b) | g(5b)<<15 | lbl(7b)<<20 |
// pos<<31 — K45 then needs no selmask/gidx/gtl pointer chase.
// ---------------------------------------------------------------------------
__global__ __launch_bounds__(1024) void k3_match_scan(
    const float* __restrict__ best_iou, const int* __restrict__ best_g_in,
    const unsigned long long* __restrict__ gkey_part, const int* __restrict__ gtl,
    int* __restrict__ gidx_out, int* __restrict__ selmask,
    unsigned long long* __restrict__ pos_key,
    int* __restrict__ pos_cnt, int* __restrict__ g_npos,
    int* __restrict__ act_list, int* __restrict__ act_cnt) {
#pragma clang fp contract(off)
    int b = blockIdx.x;
    int tid = threadIdx.x;
    int lane = tid & 63, wid = tid >> 6;
    __shared__ short s_ov[AA];                  // override g per anchor, -1 none
    __shared__ unsigned long long s_gmax[GG];
    __shared__ int sba[GG];
    __shared__ int s_gtl[GG];
    __shared__ unsigned long long s_pmask[NWCH];
    __shared__ unsigned long long s_nmask[NWCH];
    __shared__ int s_woff[NWCH];
    __shared__ int s_wred[5];
    __shared__ int s_cnt, s_act;
    for (int i = tid; i < AA; i += 1024) s_ov[i] = -1;
    if (tid < GG) { s_gmax[tid] = 0ULL; s_gtl[tid] = gtl[b * GG + tid]; }
    if (tid == 0) { s_cnt = 0; s_act = 0; }
    __syncthreads();
    // reduce 76 per-block partial keys per g (32 g x 32 groups)
    for (int c = tid >> 5; c < NB1; c += 32)
        atomicMax(&s_gmax[tid & 31],
                  gkey_part[((size_t)b * NB1 + c) * GG + (tid & 31)]);
    __syncthreads();
    if (tid < GG) sba[tid] = AA - 1 - (int)(unsigned)(s_gmax[tid] & 0xffffffffULL);
    __syncthreads();
    if (tid == 0) {
        for (int g = 0; g < GG; ++g) s_ov[sba[g]] = (short)g;  // ascending: last wins
    }
    __syncthreads();

    // pass 1: matching decisions + pos keys + per-wave-chunk ballots
    for (int base = 0; base < AA; base += 1024) {
        int a = base + tid;
        bool p = false, npre = false;
        if (a < AA) {
            float biou = best_iou[b * AA + a];
            int ov = s_ov[a];
            int gi = (ov >= 0) ? ov : best_g_in[b * AA + a];
            p = (biou >= 0.5f) || (ov >= 0);
            npre = (biou < 0.4f) && !p;
            gidx_out[b * AA + a] = gi;
            selmask[b * AA + a] = p ? 2 : (npre ? 1 : 0);
            if (p) {
                int slot = atomicAdd(&s_cnt, 1);
                unsigned vb = __float_as_uint(biou + 1.0f);   // >= 0x3F800000
                unsigned long long key =
                    ((unsigned long long)(vb - 0x3F800000u) << 32) |
                    (unsigned)(AA - 1 - a);
                pos_key[(size_t)b * AA + slot] = key;
            }
        }
        unsigned long long pm = __ballot(p);
        unsigned long long nm = __ballot(npre);
        if (lane == 0) {
            int w = (base >> 6) + wid;
            s_pmask[w] = pm;
            s_nmask[w] = nm;
        }
    }
    __syncthreads();
    int npos = s_cnt;
    if (tid == 0) { pos_cnt[b] = npos; atomicAdd(g_npos, npos); }
    int cap = npos * NEGRATIO;

    // scan 304 chunk counts with 5 waves
    int c = (tid < NWCH) ? __popcll(s_nmask[tid]) : 0;
    int inc = c;
    if (wid < 5) {
        #pragma unroll
        for (int d = 1; d < 64; d <<= 1) {
            int t = __shfl_up(inc, d);
            if (lane >= d) inc += t;
        }
        if (lane == 63) s_wred[wid] = inc;
    }
    __syncthreads();
    if (tid == 0) {
        int run = 0;
        #pragma unroll
        for (int i = 0; i < 5; ++i) { int t = s_wred[i]; s_wred[i] = run; run += t; }
    }
    __syncthreads();
    if (tid < NWCH) s_woff[tid] = inc - c + s_wred[wid];   // exclusive prefix
    __syncthreads();

    // pass 2: drop negs beyond cap, compact PACKED active rows (order-free)
    for (int base = 0; base < AA; base += 1024) {
        int a = base + tid;
        int w = (base >> 6) + wid;
        unsigned long long nm = s_nmask[w], pm = s_pmask[w];
        bool npre = (nm >> lane) & 1ULL;
        bool pos  = (pm >> lane) & 1ULL;
        int rank = __popcll(nm & ((1ULL << lane) - 1ULL));
        bool kept = npre && (s_woff[w] + rank + 1 <= cap);
        if (a < AA) {
            if (npre && !kept) selmask[b * AA + a] = 0;
            if (pos || kept) {
                int slot = atomicAdd(&s_act, 1);
                int gi = gidx_out[b * AA + a];          // same-block write, L1
                int lbl = pos ? s_gtl[gi] : 0;
                unsigned e = (unsigned)a | ((unsigned)gi << 15) |
                             ((unsigned)lbl << 20) | (pos ? 0x80000000u : 0u);
                act_list[b * AA + slot] = (int)e;
            }
        }
    }
    __syncthreads();
    if (tid == 0) act_cnt[b] = s_act;
}

// ---------------------------------------------------------------------------
// K45 v3: focal + box loss, thread-per-row; per-block partials stored to
// DEDICATED SLOTS (no global atomics — round-14 lesson: same-address atomic
// RMWs serialize ~20cyc each in one L2 atomic unit).
// ---------------------------------------------------------------------------
__global__ __launch_bounds__(256) void k45_cls_box(
    const float* __restrict__ cls_p, const int* __restrict__ act_list,
    const int* __restrict__ act_cnt, const float* __restrict__ box_p,
    const float* __restrict__ anchors, const float* __restrict__ gt_boxes,
    float* __restrict__ part_cls, float* __restrict__ part_box) {
    int b = blockIdx.y;
    int n = act_cnt[b];
    float fsum = 0.0f, bsum = 0.0f;
    for (int i = blockIdx.x * 256 + threadIdx.x; i < n; i += NB45 * 256) {
        unsigned e = (unsigned)act_list[b * AA + i];
        int a = e & 0x7fff;
        int g = (e >> 15) & 31;
        int lbl = (e >> 20) & 127;
        bool pos = (e >> 31) != 0u;
        const float* x = cls_p + (size_t)(b * AA + a) * CC;
        float v80 = x[80];
        float m0 = v80, m1 = -3.0e38f, m2 = -3.0e38f, m3 = -3.0e38f;
        #pragma unroll
        for (int q = 0; q < 20; ++q) {
            m0 = fmaxf(m0, x[4 * q + 0]); m1 = fmaxf(m1, x[4 * q + 1]);
            m2 = fmaxf(m2, x[4 * q + 2]); m3 = fmaxf(m3, x[4 * q + 3]);
        }
        float m = fmaxf(fmaxf(m0, m1), fmaxf(m2, m3));
        float s0 = __expf(v80 - m), s1 = 0.f, s2 = 0.f, s3 = 0.f;
        #pragma unroll
        for (int q = 0; q < 20; ++q) {
            s0 += __expf(x[4 * q + 0] - m); s1 += __expf(x[4 * q + 1] - m);
            s2 += __expf(x[4 * q + 2] - m); s3 += __expf(x[4 * q + 3] - m);
        }
        float s = (s0 + s1) + (s2 + s3);
        float pt = __expf(x[lbl] - m) / s;
        pt = fminf(fmaxf(pt, 1e-6f), 1.0f - 1e-6f);
        float at = (lbl > 0) ? 0.25f : 0.75f;
        float om = 1.0f - pt;
        fsum += at * om * om * (-__logf(pt));
        if (pos) {
#pragma clang fp contract(off)
            float4 mb = ((const float4*)gt_boxes)[b * GG + g];
            float4 an = ((const float4*)anchors)[a];
            const float4 bp = ((const float4*)box_p)[(size_t)b * AA + a];
            float q0 = mb.x / 550.0f, q1 = mb.y / 550.0f;
            float q2 = mb.z / 550.0f, q3 = mb.w / 550.0f;
            float gcx = 0.5f * (q0 + q2), gcy = 0.5f * (q1 + q3);
            float gw = fmaxf(q2 - q0, 1e-6f), gh = fmaxf(q3 - q1, 1e-6f);
            float t0 = (gcx - an.x) / (an.z * 0.1f);
            float t1 = (gcy - an.y) / (an.w * 0.1f);
            float t2 = logf(gw / an.z) / 0.2f;
            float t3 = logf(gh / an.w) / 0.2f;
            float d;
            d = fabsf(bp.x - t0); bsum += (d < 1.0f) ? 0.5f * d * d : d - 0.5f;
            d = fabsf(bp.y - t1); bsum += (d < 1.0f) ? 0.5f * d * d : d - 0.5f;
            d = fabsf(bp.z - t2); bsum += (d < 1.0f) ? 0.5f * d * d : d - 0.5f;
            d = fabsf(bp.w - t3); bsum += (d < 1.0f) ? 0.5f * d * d : d - 0.5f;
        }
    }
    for (int off = 32; off; off >>= 1) {
        fsum += __shfl_xor(fsum, off);
        bsum += __shfl_xor(bsum, off);
    }
    __shared__ float s4f[4], s4b[4];
    if ((threadIdx.x & 63) == 0) {
        s4f[threadIdx.x >> 6] = fsum;
        s4b[threadIdx.x >> 6] = bsum;
    }
    __syncthreads();
    if (threadIdx.x == 0) {
        part_cls[b * NB45 + blockIdx.x] = s4f[0] + s4f[1] + s4f[2] + s4f[3];
        part_box[b * NB45 + blockIdx.x] = s4b[0] + s4b[1] + s4b[2] + s4b[3];
    }
}

// ---------------------------------------------------------------------------
// K6: per-image top-min(npos,128) via MSB-first radix select, then counting-
// sort by matched gt index g. Emits f16 coeffs (RNE cvt), ZERO-PADDED to
// KPOS rows, and sel_g padded with the last (max) g so it stays monotone.
// ---------------------------------------------------------------------------
__global__ __launch_bounds__(1024) void k6_select(
    const unsigned long long* __restrict__ pos_key, const int* __restrict__ pos_cnt,
    const int* __restrict__ gidx, const float* __restrict__ coeffs,
    int* __restrict__ sel_g, _Float16* __restrict__ sel_coef,
    int* __restrict__ sel_cnt) {
    int b = blockIdx.x, tid = threadIdx.x;
    __shared__ unsigned long long s_keys[SELCAP];
    __shared__ int s_hist[256];
    __shared__ int s_sfx[256];
    __shared__ int s_wsum[4];
    __shared__ unsigned long long s_prefix;
    __shared__ int s_kk;
    __shared__ int s_nsel;
    __shared__ int s_sel_a[KPOS];
    __shared__ int s_sorted_a[KPOS];
    __shared__ int s_sorted_g[KPOS];
    __shared__ int s_gcnt[GG];

    int n = pos_cnt[b];
    int K = (n < KPOS) ? n : KPOS;
    const unsigned long long* keys;
    if (n <= SELCAP) {
        for (int i = tid; i < n; i += 1024) s_keys[i] = pos_key[(size_t)b * AA + i];
        keys = s_keys;
    } else {
        keys = pos_key + (size_t)b * AA;
    }
    if (tid == 0) { s_prefix = 0ULL; s_kk = KPOS; s_nsel = 0; }
    __syncthreads();

    if (n > KPOS) {
        for (int d = 6; d >= 0; --d) {
            unsigned long long pref = s_prefix;   // snapshot (post-barrier)
            int kk = s_kk;
            if (tid < 256) s_hist[tid] = 0;
            __syncthreads();
            unsigned long long mhi = ~((1ULL << (8 * (d + 1))) - 1ULL);
            for (int i = tid; i < n; i += 1024) {
                unsigned long long k = keys[i];
                if ((k & mhi) == pref)
                    atomicAdd(&s_hist[(int)((k >> (8 * d)) & 255)], 1);
            }
            __syncthreads();
            int x = 0;
            if (tid < 256) {
                x = s_hist[255 - tid];
                #pragma unroll
                for (int o = 1; o < 64; o <<= 1) {
                    int t = __shfl_up(x, o);
                    if ((tid & 63) >= o) x += t;
                }
                if ((tid & 63) == 63) s_wsum[tid >> 6] = x;
            }
            __syncthreads();
            if (tid == 0) {
                int run = 0;
                #pragma unroll
                for (int i = 0; i < 4; ++i) { int t = s_wsum[i]; s_wsum[i] = run; run += t; }
            }
            __syncthreads();
            if (tid < 256) s_sfx[255 - tid] = x + s_wsum[tid >> 6];
            __syncthreads();
            if (tid < 256) {
                int v = tid;
                int ge = s_sfx[v];
                int gt = (v == 255) ? 0 : s_sfx[v + 1];
                if (ge >= kk && gt < kk) {
                    s_prefix = pref | ((unsigned long long)v << (8 * d));
                    s_kk = kk - gt;
                }
            }
            __syncthreads();
        }
    }

    unsigned long long T = (n > KPOS) ? s_prefix : 0ULL;
    for (int i = tid; i < n; i += 1024) {
        unsigned long long k = keys[i];
        if (k >= T) {
            int slot = atomicAdd(&s_nsel, 1);
            if (slot < KPOS)
                s_sel_a[slot] = AA - 1 - (int)(unsigned)(k & 0xffffffffu);
        }
    }
    __syncthreads();

    if (tid < GG) s_gcnt[tid] = 0;
    __syncthreads();
    int mya = -1, myg = -1;
    if (tid < K) {
        mya = s_sel_a[tid];
        myg = gidx[b * AA + mya];
        atomicAdd(&s_gcnt[myg], 1);
    }
    __syncthreads();
    if (tid == 0) {
        int run = 0;
        for (int g = 0; g < GG; ++g) { int c = s_gcnt[g]; s_gcnt[g] = run; run += c; }
    }
    __syncthreads();
    if (tid < K) {
        int pos = atomicAdd(&s_gcnt[myg], 1);
        s_sorted_a[pos] = mya;
        s_sorted_g[pos] = myg;
    }
    __syncthreads();

    if (tid == 0) sel_cnt[b] = K;
    int glast = (K > 0) ? s_sorted_g[K - 1] : 0;
    for (int t = tid; t < KPOS * PP; t += 1024) {
        int k = t >> 5, p = t & 31;
        _Float16 v = (_Float16)0.0f;
        if (k < K) {
            int a = s_sorted_a[k];
            v = (_Float16)coeffs[((size_t)(b * AA + a)) * PP + p];
        }
        sel_coef[(size_t)(b * KPOS + k) * PP + p] = v;
    }
    for (int t = tid; t < KPOS; t += 1024)
        sel_g[b * KPOS + t] = (t < K) ? s_sorted_g[t] : glast;
}

// ---------------------------------------------------------------------------
// K7 v10: MFMA mask loss — no break (padding makes all 8 k-tiles safe: zero
// coeffs -> masked by k<nk; padded g valid), ALL 16 loads preloaded up front
// (one latency), 8 back-to-back MFMAs, pure-VALU epilogue, and the block
// partial goes to a DEDICATED slot (no same-address atomic drain tail —
// that tail was the invariant ~39 us floor across rounds 11-14).
// ---------------------------------------------------------------------------
__global__ __launch_bounds__(256) void k7_mask(
    const _Float16* __restrict__ protoT, const unsigned* __restrict__ pmask,
    const _Float16* __restrict__ sel_coef, const int* __restrict__ sel_g,
    const int* __restrict__ sel_cnt, float* __restrict__ part_mask) {
    int b = blockIdx.y;
    int nk = sel_cnt[b];
    int tid = threadIdx.x;
    int wave = tid >> 6, lane = tid & 63;
    int lg = lane >> 4;                       // lane group 0..3
    int ln = lane & 15;                       // n (px) / A-row (k) index
    int pt = blockIdx.x * 4 + wave;           // pixel-tile index
    int px = pt * 16 + ln;
    bool pxv = (pt < NPT) && (px < PHW);
    int pc = pxv ? px : PHW - 1;

    half8 bfrag = *(const half8*)&protoT[((size_t)b * PHW + pc) * PP + lg * 8];
    unsigned gmask = pmask[(size_t)b * PHW + pc];

    const _Float16* ca = sel_coef + (size_t)b * KPOS * PP;
    const int* gb = sel_g + b * KPOS;

    // preload all 8 A-frags and g-vectors: 16 independent loads, one latency
    half8 af[8];
    int4 gv[8];
    #pragma unroll
    for (int kt = 0; kt < 8; ++kt) {
        af[kt] = *(const half8*)&ca[(size_t)(kt * 16 + ln) * PP + lg * 8];
        gv[kt] = *(const int4*)&gb[kt * 16 + lg * 4];
    }

    float acc = 0.0f;
    #pragma unroll
    for (int kt = 0; kt < 8; ++kt) {
        floatx4 c = {0.f, 0.f, 0.f, 0.f};
        c = __builtin_amdgcn_mfma_f32_16x16x32_f16(af[kt], bfrag, c, 0, 0, 0);
        #pragma unroll
        for (int r = 0; r < 4; ++r) {
            int k = kt * 16 + lg * 4 + r;
            float l = c[r];
            int g0 = (r == 0) ? gv[kt].x : (r == 1) ? gv[kt].y
                   : (r == 2) ? gv[kt].z : gv[kt].w;
            float t = (float)((gmask >> g0) & 1u);
            float bce = fmaxf(l, 0.f) - l * t + __logf(1.f + __expf(-fabsf(l)));
            if (pxv && k < nk) acc += bce;
        }
    }

    for (int off = 32; off; off >>= 1) acc += __shfl_xor(acc, off);
    __shared__ float s_red[4];
    if (lane == 0) s_red[wave] = acc;
    __syncthreads();
    if (tid == 0)
        part_mask[(size_t)b * NB7 + blockIdx.x] =
            s_red[0] + s_red[1] + s_red[2] + s_red[3];
}

// ---------------------------------------------------------------------------
// K8 v2: final reduction over all per-block partials (2384 + 256 + 256) —
// replaces the same-address atomic accumulators entirely.
// ---------------------------------------------------------------------------
__global__ __launch_bounds__(1024) void k8_final(
    const float* __restrict__ part_cls, const float* __restrict__ part_box,
    const float* __restrict__ part_mask, const int* __restrict__ npos,
    float* __restrict__ out) {
    int tid = threadIdx.x;
    float c = 0.f, bx = 0.f, mk = 0.f;
    for (int i = tid; i < NB45 * BB; i += 1024) {
        c += part_cls[i];
        bx += part_box[i];
    }
    for (int i = tid; i < NB7 * BB; i += 1024)
        mk += part_mask[i];
    for (int off = 32; off; off >>= 1) {
        c += __shfl_xor(c, off);
        bx += __shfl_xor(bx, off);
        mk += __shfl_xor(mk, off);
    }
    __shared__ float sc[16], sb[16], sm[16];
    if ((tid & 63) == 0) {
        sc[tid >> 6] = c; sb[tid >> 6] = bx; sm[tid >> 6] = mk;
    }
    __syncthreads();
    if (tid == 0) {
        float tc = 0.f, tb = 0.f, tm = 0.f;
        #pragma unroll
        for (int i = 0; i < 16; ++i) { tc += sc[i]; tb += sb[i]; tm += sm[i]; }
        float denom = fmaxf((float)(*npos), 1.0f);
        out[0] = (1.0f * tc + 1.5f * tb + 6.125f * (tm / (float)PHW)) / denom;
    }
}

// ---------------------------------------------------------------------------
extern "C" void kernel_launch(void* const* d_in, const int* in_sizes, int n_in,
                              void* d_out, int out_size, void* d_ws, size_t ws_size,
                              hipStream_t stream) {
    (void)in_sizes; (void)n_in; (void)out_size; (void)ws_size;
    const float* class_preds = (const float*)d_in[0];
    const float* box_preds   = (const float*)d_in[1];
    const float* mask_coeffs = (const float*)d_in[2];
    const float* prototypes  = (const float*)d_in[3];
    const float* anchors     = (const float*)d_in[4];
    const float* gt_boxes    = (const float*)d_in[5];
    const int*   gt_labels   = (const int*)d_in[6];
    const float* gt_masks    = (const float*)d_in[7];
    float* out = (float*)d_out;

    size_t off = 0;
    char* w = (char*)d_ws;
    auto take = [&](size_t bytes) -> char* {
        char* p = w + off;
        off += (bytes + 255) & ~(size_t)255;
        return p;
    };
    float* acc      = (float*)take(32);                       // [.,.,., npos(int)]
    float* best_iou = (float*)take((size_t)BB * AA * 4);
    int*   best_g   = (int*)  take((size_t)BB * AA * 4);
    int*   gidx     = (int*)  take((size_t)BB * AA * 4);
    int*   selmask  = (int*)  take((size_t)BB * AA * 4);
    unsigned long long* gkey_part =
        (unsigned long long*)take((size_t)BB * NB1 * GG * 8);
    int*   pos_cnt  = (int*)  take((size_t)BB * 4);
    unsigned long long* pos_key = (unsigned long long*)take((size_t)BB * AA * 8);
    int*   sel_g    = (int*)  take((size_t)BB * KPOS * 4);
    int*   sel_cnt  = (int*)  take((size_t)BB * 4);
    _Float16* sel_coef = (_Float16*)take((size_t)BB * KPOS * PP * 2);
    int*   act_list = (int*)  take((size_t)BB * AA * 4);
    int*   act_cnt  = (int*)  take((size_t)BB * 4);
    _Float16* protoT = (_Float16*)take((size_t)BB * PHW * PP * 2);
    unsigned* pmaskb = (unsigned*)take((size_t)BB * PHW * 4);
    float* part_cls  = (float*)take((size_t)BB * NB45 * 4);
    float* part_box  = (float*)take((size_t)BB * NB45 * 4);
    float* part_mask = (float*)take((size_t)BB * NB7 * 4);

    k0_prep<<<dim3((PHW + 255) / 256, BB), 256, 0, stream>>>(
        prototypes, gt_masks, protoT, pmaskb);
    k1_match<<<dim3(NB1, BB), 256, 0, stream>>>(
        anchors, gt_boxes, best_iou, best_g, gkey_part, acc);
    k3_match_scan<<<BB, 1024, 0, stream>>>(
        best_iou, best_g, gkey_part, gt_labels, gidx, selmask, pos_key, pos_cnt,
        (int*)(acc + 3), act_list, act_cnt);
    k45_cls_box<<<dim3(NB45, BB), 256, 0, stream>>>(
        class_preds, act_list, act_cnt, box_preds, anchors, gt_boxes,
        part_cls, part_box);
    k6_select<<<BB, 1024, 0, stream>>>(
        pos_key, pos_cnt, gidx, mask_coeffs, sel_g, sel_coef, sel_cnt);
    k7_mask<<<dim3(NB7, BB), 256, 0, stream>>>(
        protoT, pmaskb, sel_coef, sel_g, sel_cnt, part_mask);
    k8_final<<<1, 1024, 0, stream>>>(
        part_cls, part_box, part_mask, (int*)(acc + 3), out);
}

// Round 16
// 74.008 us; speedup vs baseline: 1.7565x; 1.1361x over previous
//
#include <hip/hip_runtime.h>
#include <math.h>

#define BB 8
#define AA 19248
#define GG 32
#define CC 81
#define PP 32
#define PHW 19044   /* 138*138 */
#define KPOS 128
#define NEGRATIO 3
#define SELCAP 7680
#define NWCH 304    /* 19 outer iters x 16 waves of 64 anchors */
#define NB1 76      /* k1-role blocks per image = ceil(AA/256) */
#define NB0 75      /* k0-role blocks per image = ceil(PHW/256) */
#define NPT 1191    /* pixel tiles of 16 = ceil(PHW/16) */
#define NB7 298     /* k7 blocks per image = ceil(NPT/4) */
#define NB45 8      /* k45-role blocks per image (1024 threads each) */

typedef _Float16 half8 __attribute__((ext_vector_type(8)));
typedef float floatx4 __attribute__((ext_vector_type(4)));

// ---------------------------------------------------------------------------
// IoU helper — contraction off so every recomputation produces bitwise-
// identical values and FMA fusion can't flip threshold/argmax decisions.
// ---------------------------------------------------------------------------
__device__ __forceinline__ float iou_one(float ax1, float ay1, float ax2, float ay2,
                                         float areaA,
                                         float gx1, float gy1, float gx2, float gy2) {
#pragma clang fp contract(off)
    float ix1 = fmaxf(ax1, gx1), iy1 = fmaxf(ay1, gy1);
    float ix2 = fminf(ax2, gx2), iy2 = fminf(ay2, gy2);
    float iw = fmaxf(ix2 - ix1, 0.0f), ih = fmaxf(iy2 - iy1, 0.0f);
    float inter = iw * ih;
    float areaB = (gx2 - gx1) * (gy2 - gy1);
    float u = areaA + areaB - inter;
    u = fmaxf(u, 1e-6f);
    return inter / u;
}

// ---------------------------------------------------------------------------
// K01: FUSED k0_prep + k1_match (independent stages; memory-bound prep
// overlaps VALU-bound matching instead of serializing — round-15: pipeline
// overhead, not kernel cost, dominates).
//   blockIdx.x <  NB1 : k1 role — per (b,a) best IoU + argmax + per-(b,g)
//                       best-anchor partial keys.
//   blockIdx.x >= NB1 : k0 role — pack binary gt-masks into u32 + transpose
//                       protos to [b][px][32] f16.
// ---------------------------------------------------------------------------
__global__ __launch_bounds__(256) void k01(
    const float* __restrict__ anchors, const float* __restrict__ gt_boxes,
    const float* __restrict__ protos, const float* __restrict__ gtm,
    float* __restrict__ best_iou, int* __restrict__ best_g,
    unsigned long long* __restrict__ gkey_part, float* __restrict__ acc,
    _Float16* __restrict__ protoT, unsigned* __restrict__ pmask) {
#pragma clang fp contract(off)
    int b = blockIdx.y;
    __shared__ float sg[GG][4];
    __shared__ unsigned long long s_gk[GG];

    if (blockIdx.x >= NB1) {
        // ---- k0 role: streaming prep ----
        int px = (blockIdx.x - NB1) * 256 + threadIdx.x;
        if (px >= PHW) return;
        const float* pb = protos + (size_t)b * PP * PHW + px;
        _Float16 v[PP];
        #pragma unroll
        for (int k = 0; k < PP; ++k)
            v[k] = (_Float16)pb[(size_t)k * PHW];
        half8* dst = (half8*)&protoT[((size_t)b * PHW + px) * PP];
        #pragma unroll
        for (int q = 0; q < 4; ++q)
            dst[q] = *(half8*)&v[q * 8];
        const float* gb = gtm + (size_t)b * GG * PHW + px;
        unsigned m = 0u;
        #pragma unroll
        for (int g = 0; g < GG; ++g)
            m |= (gb[(size_t)g * PHW] > 0.5f) ? (1u << g) : 0u;
        pmask[(size_t)b * PHW + px] = m;
        return;
    }

    // ---- k1 role: matching ----
    int a = blockIdx.x * 256 + threadIdx.x;
    int lane = threadIdx.x & 63;
    if (blockIdx.x == 0 && b == 0 && threadIdx.x < 4)
        ((int*)acc)[threadIdx.x] = 0;            // zero [., ., ., npos]
    for (int t = threadIdx.x; t < GG * 4; t += 256)
        sg[t >> 2][t & 3] = gt_boxes[b * GG * 4 + t] / 550.0f;
    if (threadIdx.x < GG) s_gk[threadIdx.x] = 0ULL;
    __syncthreads();
    bool valid = a < AA;
    int ac = valid ? a : AA - 1;
    float4 an = ((const float4*)anchors)[ac];
    float ax1 = an.x - an.z * 0.5f, ay1 = an.y - an.w * 0.5f;
    float ax2 = an.x + an.z * 0.5f, ay2 = an.y + an.w * 0.5f;
    float areaA = (ax2 - ax1) * (ay2 - ay1);
    unsigned long long bk = 0ULL;   // (vbits<<6)|(31-g): max => first-max argmax
    for (int gg = 0; gg < GG; ++gg) {
        int g = (gg + lane) & (GG - 1);          // stagger: 32 distinct LDS slots
        float v = iou_one(ax1, ay1, ax2, ay2, areaA, sg[g][0], sg[g][1], sg[g][2], sg[g][3]);
        unsigned vb = __float_as_uint(v);        // v >= 0 -> order-preserving
        unsigned long long k2 = ((unsigned long long)vb << 6) | (unsigned)(GG - 1 - g);
        if (k2 > bk) bk = k2;
        if (valid) {
            unsigned long long kg =
                ((unsigned long long)vb << 32) | (unsigned)(AA - 1 - a);
            atomicMax(&s_gk[g], kg);
        }
    }
    if (valid) {
        best_iou[b * AA + a] = __uint_as_float((unsigned)(bk >> 6));
        best_g[b * AA + a] = (GG - 1) - (int)(bk & 63ULL);
    }
    __syncthreads();
    if (threadIdx.x < GG)
        gkey_part[((size_t)b * NB1 + blockIdx.x) * GG + threadIdx.x] = s_gk[threadIdx.x];
}

// ---------------------------------------------------------------------------
// K3: per image — reduce per-block gt keys, scatter overrides via an O(1) LDS
// lookup table (ascending g -> last wins, matching XLA scatter), pos
// compaction + keys, hard-negative cap via ballot-based scan, active-row
// compaction. act_list entries PACKED: a | g<<15 | lbl<<20 | pos<<31.
// ---------------------------------------------------------------------------
__global__ __launch_bounds__(1024) void k3_match_scan(
    const float* __restrict__ best_iou, const int* __restrict__ best_g_in,
    const unsigned long long* __restrict__ gkey_part, const int* __restrict__ gtl,
    int* __restrict__ gidx_out, int* __restrict__ selmask,
    unsigned long long* __restrict__ pos_key,
    int* __restrict__ pos_cnt, int* __restrict__ g_npos,
    int* __restrict__ act_list, int* __restrict__ act_cnt) {
#pragma clang fp contract(off)
    int b = blockIdx.x;
    int tid = threadIdx.x;
    int lane = tid & 63, wid = tid >> 6;
    __shared__ short s_ov[AA];                  // override g per anchor, -1 none
    __shared__ unsigned long long s_gmax[GG];
    __shared__ int sba[GG];
    __shared__ int s_gtl[GG];
    __shared__ unsigned long long s_pmask[NWCH];
    __shared__ unsigned long long s_nmask[NWCH];
    __shared__ int s_woff[NWCH];
    __shared__ int s_wred[5];
    __shared__ int s_cnt, s_act;
    for (int i = tid; i < AA; i += 1024) s_ov[i] = -1;
    if (tid < GG) { s_gmax[tid] = 0ULL; s_gtl[tid] = gtl[b * GG + tid]; }
    if (tid == 0) { s_cnt = 0; s_act = 0; }
    __syncthreads();
    // reduce 76 per-block partial keys per g (32 g x 32 groups)
    for (int c = tid >> 5; c < NB1; c += 32)
        atomicMax(&s_gmax[tid & 31],
                  gkey_part[((size_t)b * NB1 + c) * GG + (tid & 31)]);
    __syncthreads();
    if (tid < GG) sba[tid] = AA - 1 - (int)(unsigned)(s_gmax[tid] & 0xffffffffULL);
    __syncthreads();
    if (tid == 0) {
        for (int g = 0; g < GG; ++g) s_ov[sba[g]] = (short)g;  // ascending: last wins
    }
    __syncthreads();

    // pass 1: matching decisions + pos keys + per-wave-chunk ballots
    for (int base = 0; base < AA; base += 1024) {
        int a = base + tid;
        bool p = false, npre = false;
        if (a < AA) {
            float biou = best_iou[b * AA + a];
            int ov = s_ov[a];
            int gi = (ov >= 0) ? ov : best_g_in[b * AA + a];
            p = (biou >= 0.5f) || (ov >= 0);
            npre = (biou < 0.4f) && !p;
            gidx_out[b * AA + a] = gi;
            selmask[b * AA + a] = p ? 2 : (npre ? 1 : 0);
            if (p) {
                int slot = atomicAdd(&s_cnt, 1);
                unsigned vb = __float_as_uint(biou + 1.0f);   // >= 0x3F800000
                unsigned long long key =
                    ((unsigned long long)(vb - 0x3F800000u) << 32) |
                    (unsigned)(AA - 1 - a);
                pos_key[(size_t)b * AA + slot] = key;
            }
        }
        unsigned long long pm = __ballot(p);
        unsigned long long nm = __ballot(npre);
        if (lane == 0) {
            int w = (base >> 6) + wid;
            s_pmask[w] = pm;
            s_nmask[w] = nm;
        }
    }
    __syncthreads();
    int npos = s_cnt;
    if (tid == 0) { pos_cnt[b] = npos; atomicAdd(g_npos, npos); }
    int cap = npos * NEGRATIO;

    // scan 304 chunk counts with 5 waves
    int c = (tid < NWCH) ? __popcll(s_nmask[tid]) : 0;
    int inc = c;
    if (wid < 5) {
        #pragma unroll
        for (int d = 1; d < 64; d <<= 1) {
            int t = __shfl_up(inc, d);
            if (lane >= d) inc += t;
        }
        if (lane == 63) s_wred[wid] = inc;
    }
    __syncthreads();
    if (tid == 0) {
        int run = 0;
        #pragma unroll
        for (int i = 0; i < 5; ++i) { int t = s_wred[i]; s_wred[i] = run; run += t; }
    }
    __syncthreads();
    if (tid < NWCH) s_woff[tid] = inc - c + s_wred[wid];   // exclusive prefix
    __syncthreads();

    // pass 2: drop negs beyond cap, compact PACKED active rows (order-free)
    for (int base = 0; base < AA; base += 1024) {
        int a = base + tid;
        int w = (base >> 6) + wid;
        unsigned long long nm = s_nmask[w], pm = s_pmask[w];
        bool npre = (nm >> lane) & 1ULL;
        bool pos  = (pm >> lane) & 1ULL;
        int rank = __popcll(nm & ((1ULL << lane) - 1ULL));
        bool kept = npre && (s_woff[w] + rank + 1 <= cap);
        if (a < AA) {
            if (npre && !kept) selmask[b * AA + a] = 0;
            if (pos || kept) {
                int slot = atomicAdd(&s_act, 1);
                int gi = gidx_out[b * AA + a];          // same-block write, L1
                int lbl = pos ? s_gtl[gi] : 0;
                unsigned e = (unsigned)a | ((unsigned)gi << 15) |
                             ((unsigned)lbl << 20) | (pos ? 0x80000000u : 0u);
                act_list[b * AA + slot] = (int)e;
            }
        }
    }
    __syncthreads();
    if (tid == 0) act_cnt[b] = s_act;
}

// ---------------------------------------------------------------------------
// K456: FUSED k45 (focal+box, thread-per-row) + k6 (radix top-K select) —
// both depend only on K3; fusing makes them co-resident.
//   blockIdx.x <  NB45 : k45 role (1024 threads, grid-stride over act rows).
//   blockIdx.x == NB45 : k6 role (the original 1024-thread select).
// ---------------------------------------------------------------------------
__global__ __launch_bounds__(1024) void k456(
    const float* __restrict__ cls_p, const int* __restrict__ act_list,
    const int* __restrict__ act_cnt, const float* __restrict__ box_p,
    const float* __restrict__ anchors, const float* __restrict__ gt_boxes,
    float* __restrict__ part_cls, float* __restrict__ part_box,
    const unsigned long long* __restrict__ pos_key, const int* __restrict__ pos_cnt,
    const int* __restrict__ gidx, const float* __restrict__ coeffs,
    int* __restrict__ sel_g, _Float16* __restrict__ sel_coef,
    int* __restrict__ sel_cnt) {
    int b = blockIdx.y;
    int tid = threadIdx.x;

    __shared__ unsigned long long s_keys[SELCAP];
    __shared__ int s_hist[256];
    __shared__ int s_sfx[256];
    __shared__ int s_wsum[4];
    __shared__ unsigned long long s_prefix;
    __shared__ int s_kk;
    __shared__ int s_nsel;
    __shared__ int s_sel_a[KPOS];
    __shared__ int s_sorted_a[KPOS];
    __shared__ int s_sorted_g[KPOS];
    __shared__ int s_gcnt[GG];
    __shared__ float s16a[16], s16b[16];

    if (blockIdx.x < NB45) {
        // ---- k45 role ----
        int n = act_cnt[b];
        float fsum = 0.0f, bsum = 0.0f;
        for (int i = blockIdx.x * 1024 + tid; i < n; i += NB45 * 1024) {
            unsigned e = (unsigned)act_list[b * AA + i];
            int a = e & 0x7fff;
            int g = (e >> 15) & 31;
            int lbl = (e >> 20) & 127;
            bool pos = (e >> 31) != 0u;
            const float* x = cls_p + (size_t)(b * AA + a) * CC;
            float v80 = x[80];
            float m0 = v80, m1 = -3.0e38f, m2 = -3.0e38f, m3 = -3.0e38f;
            #pragma unroll
            for (int q = 0; q < 20; ++q) {
                m0 = fmaxf(m0, x[4 * q + 0]); m1 = fmaxf(m1, x[4 * q + 1]);
                m2 = fmaxf(m2, x[4 * q + 2]); m3 = fmaxf(m3, x[4 * q + 3]);
            }
            float m = fmaxf(fmaxf(m0, m1), fmaxf(m2, m3));
            float s0 = __expf(v80 - m), s1 = 0.f, s2 = 0.f, s3 = 0.f;
            #pragma unroll
            for (int q = 0; q < 20; ++q) {
                s0 += __expf(x[4 * q + 0] - m); s1 += __expf(x[4 * q + 1] - m);
                s2 += __expf(x[4 * q + 2] - m); s3 += __expf(x[4 * q + 3] - m);
            }
            float s = (s0 + s1) + (s2 + s3);
            float pt = __expf(x[lbl] - m) / s;
            pt = fminf(fmaxf(pt, 1e-6f), 1.0f - 1e-6f);
            float at = (lbl > 0) ? 0.25f : 0.75f;
            float om = 1.0f - pt;
            fsum += at * om * om * (-__logf(pt));
            if (pos) {
#pragma clang fp contract(off)
                float4 mb = ((const float4*)gt_boxes)[b * GG + g];
                float4 an = ((const float4*)anchors)[a];
                const float4 bp = ((const float4*)box_p)[(size_t)b * AA + a];
                float q0 = mb.x / 550.0f, q1 = mb.y / 550.0f;
                float q2 = mb.z / 550.0f, q3 = mb.w / 550.0f;
                float gcx = 0.5f * (q0 + q2), gcy = 0.5f * (q1 + q3);
                float gw = fmaxf(q2 - q0, 1e-6f), gh = fmaxf(q3 - q1, 1e-6f);
                float t0 = (gcx - an.x) / (an.z * 0.1f);
                float t1 = (gcy - an.y) / (an.w * 0.1f);
                float t2 = logf(gw / an.z) / 0.2f;
                float t3 = logf(gh / an.w) / 0.2f;
                float d;
                d = fabsf(bp.x - t0); bsum += (d < 1.0f) ? 0.5f * d * d : d - 0.5f;
                d = fabsf(bp.y - t1); bsum += (d < 1.0f) ? 0.5f * d * d : d - 0.5f;
                d = fabsf(bp.z - t2); bsum += (d < 1.0f) ? 0.5f * d * d : d - 0.5f;
                d = fabsf(bp.w - t3); bsum += (d < 1.0f) ? 0.5f * d * d : d - 0.5f;
            }
        }
        for (int off = 32; off; off >>= 1) {
            fsum += __shfl_xor(fsum, off);
            bsum += __shfl_xor(bsum, off);
        }
        if ((tid & 63) == 0) { s16a[tid >> 6] = fsum; s16b[tid >> 6] = bsum; }
        __syncthreads();
        if (tid == 0) {
            float tf = 0.f, tb = 0.f;
            #pragma unroll
            for (int i = 0; i < 16; ++i) { tf += s16a[i]; tb += s16b[i]; }
            part_cls[b * NB45 + blockIdx.x] = tf;
            part_box[b * NB45 + blockIdx.x] = tb;
        }
        return;
    }

    // ---- k6 role ----
    int n = pos_cnt[b];
    int K = (n < KPOS) ? n : KPOS;
    const unsigned long long* keys;
    if (n <= SELCAP) {
        for (int i = tid; i < n; i += 1024) s_keys[i] = pos_key[(size_t)b * AA + i];
        keys = s_keys;
    } else {
        keys = pos_key + (size_t)b * AA;
    }
    if (tid == 0) { s_prefix = 0ULL; s_kk = KPOS; s_nsel = 0; }
    __syncthreads();

    if (n > KPOS) {
        for (int d = 6; d >= 0; --d) {
            unsigned long long pref = s_prefix;   // snapshot (post-barrier)
            int kk = s_kk;
            int lane = tid & 63;
            if (tid < 256) s_hist[tid] = 0;
            __syncthreads();
            unsigned long long mhi = ~((1ULL << (8 * (d + 1))) - 1ULL);
            for (int i = tid; i < n; i += 1024) {
                unsigned long long k = keys[i];
                if ((k & mhi) == pref)
                    atomicAdd(&s_hist[(int)((k >> (8 * d)) & 255)], 1);
            }
            __syncthreads();
            int x = 0;
            if (tid < 256) {
                x = s_hist[255 - tid];
                #pragma unroll
                for (int o = 1; o < 64; o <<= 1) {
                    int t = __shfl_up(x, o);
                    if (lane >= o) x += t;
                }
                if (lane == 63) s_wsum[tid >> 6] = x;
            }
            __syncthreads();
            if (tid == 0) {
                int run = 0;
                #pragma unroll
                for (int i = 0; i < 4; ++i) { int t = s_wsum[i]; s_wsum[i] = run; run += t; }
            }
            __syncthreads();
            if (tid < 256) s_sfx[255 - tid] = x + s_wsum[tid >> 6];
            __syncthreads();
            if (tid < 256) {
                int v = tid;
                int ge = s_sfx[v];
                int gt = (v == 255) ? 0 : s_sfx[v + 1];
                if (ge >= kk && gt < kk) {
                    s_prefix = pref | ((unsigned long long)v << (8 * d));
                    s_kk = kk - gt;
                }
            }
            __syncthreads();
        }
    }

    unsigned long long T = (n > KPOS) ? s_prefix : 0ULL;
    for (int i = tid; i < n; i += 1024) {
        unsigned long long k = keys[i];
        if (k >= T) {
            int slot = atomicAdd(&s_nsel, 1);
            if (slot < KPOS)
                s_sel_a[slot] = AA - 1 - (int)(unsigned)(k & 0xffffffffu);
        }
    }
    __syncthreads();

    if (tid < GG) s_gcnt[tid] = 0;
    __syncthreads();
    int mya = -1, myg = -1;
    if (tid < K) {
        mya = s_sel_a[tid];
        myg = gidx[b * AA + mya];
        atomicAdd(&s_gcnt[myg], 1);
    }
    __syncthreads();
    if (tid == 0) {
        int run = 0;
        for (int g = 0; g < GG; ++g) { int c = s_gcnt[g]; s_gcnt[g] = run; run += c; }
    }
    __syncthreads();
    if (tid < K) {
        int pos = atomicAdd(&s_gcnt[myg], 1);
        s_sorted_a[pos] = mya;
        s_sorted_g[pos] = myg;
    }
    __syncthreads();

    if (tid == 0) sel_cnt[b] = K;
    int glast = (K > 0) ? s_sorted_g[K - 1] : 0;
    for (int t = tid; t < KPOS * PP; t += 1024) {
        int k = t >> 5, p = t & 31;
        _Float16 v = (_Float16)0.0f;
        if (k < K) {
            int a = s_sorted_a[k];
            v = (_Float16)coeffs[((size_t)(b * AA + a)) * PP + p];
        }
        sel_coef[(size_t)(b * KPOS + k) * PP + p] = v;
    }
    for (int t = tid; t < KPOS; t += 1024)
        sel_g[b * KPOS + t] = (t < K) ? s_sorted_g[t] : glast;
}

// ---------------------------------------------------------------------------
// K7: MFMA mask loss — all 16 loads preloaded (one latency), 8 back-to-back
// MFMAs, memory-free pure-VALU BCE epilogue (gmask bit test), block partial
// to a DEDICATED slot (no same-address atomic drain tail).
// ---------------------------------------------------------------------------
__global__ __launch_bounds__(256) void k7_mask(
    const _Float16* __restrict__ protoT, const unsigned* __restrict__ pmask,
    const _Float16* __restrict__ sel_coef, const int* __restrict__ sel_g,
    const int* __restrict__ sel_cnt, float* __restrict__ part_mask) {
    int b = blockIdx.y;
    int nk = sel_cnt[b];
    int tid = threadIdx.x;
    int wave = tid >> 6, lane = tid & 63;
    int lg = lane >> 4;                       // lane group 0..3
    int ln = lane & 15;                       // n (px) / A-row (k) index
    int pt = blockIdx.x * 4 + wave;           // pixel-tile index
    int px = pt * 16 + ln;
    bool pxv = (pt < NPT) && (px < PHW);
    int pc = pxv ? px : PHW - 1;

    half8 bfrag = *(const half8*)&protoT[((size_t)b * PHW + pc) * PP + lg * 8];
    unsigned gmask = pmask[(size_t)b * PHW + pc];

    const _Float16* ca = sel_coef + (size_t)b * KPOS * PP;
    const int* gb = sel_g + b * KPOS;

    half8 af[8];
    int4 gv[8];
    #pragma unroll
    for (int kt = 0; kt < 8; ++kt) {
        af[kt] = *(const half8*)&ca[(size_t)(kt * 16 + ln) * PP + lg * 8];
        gv[kt] = *(const int4*)&gb[kt * 16 + lg * 4];
    }

    float acc = 0.0f;
    #pragma unroll
    for (int kt = 0; kt < 8; ++kt) {
        floatx4 c = {0.f, 0.f, 0.f, 0.f};
        c = __builtin_amdgcn_mfma_f32_16x16x32_f16(af[kt], bfrag, c, 0, 0, 0);
        #pragma unroll
        for (int r = 0; r < 4; ++r) {
            int k = kt * 16 + lg * 4 + r;
            float l = c[r];
            int g0 = (r == 0) ? gv[kt].x : (r == 1) ? gv[kt].y
                   : (r == 2) ? gv[kt].z : gv[kt].w;
            float t = (float)((gmask >> g0) & 1u);
            float bce = fmaxf(l, 0.f) - l * t + __logf(1.f + __expf(-fabsf(l)));
            if (pxv && k < nk) acc += bce;
        }
    }

    for (int off = 32; off; off >>= 1) acc += __shfl_xor(acc, off);
    __shared__ float s_red[4];
    if (lane == 0) s_red[wave] = acc;
    __syncthreads();
    if (tid == 0)
        part_mask[(size_t)b * NB7 + blockIdx.x] =
            s_red[0] + s_red[1] + s_red[2] + s_red[3];
}

// ---------------------------------------------------------------------------
// K8: final reduction over all per-block partials.
// ---------------------------------------------------------------------------
__global__ __launch_bounds__(1024) void k8_final(
    const float* __restrict__ part_cls, const float* __restrict__ part_box,
    const float* __restrict__ part_mask, const int* __restrict__ npos,
    float* __restrict__ out) {
    int tid = threadIdx.x;
    float c = 0.f, bx = 0.f, mk = 0.f;
    for (int i = tid; i < NB45 * BB; i += 1024) {
        c += part_cls[i];
        bx += part_box[i];
    }
    for (int i = tid; i < NB7 * BB; i += 1024)
        mk += part_mask[i];
    for (int off = 32; off; off >>= 1) {
        c += __shfl_xor(c, off);
        bx += __shfl_xor(bx, off);
        mk += __shfl_xor(mk, off);
    }
    __shared__ float sc[16], sb[16], sm[16];
    if ((tid & 63) == 0) {
        sc[tid >> 6] = c; sb[tid >> 6] = bx; sm[tid >> 6] = mk;
    }
    __syncthreads();
    if (tid == 0) {
        float tc = 0.f, tb = 0.f, tm = 0.f;
        #pragma unroll
        for (int i = 0; i < 16; ++i) { tc += sc[i]; tb += sb[i]; tm += sm[i]; }
        float denom = fmaxf((float)(*npos), 1.0f);
        out[0] = (1.0f * tc + 1.5f * tb + 6.125f * (tm / (float)PHW)) / denom;
    }
}

// ---------------------------------------------------------------------------
extern "C" void kernel_launch(void* const* d_in, const int* in_sizes, int n_in,
                              void* d_out, int out_size, void* d_ws, size_t ws_size,
                              hipStream_t stream) {
    (void)in_sizes; (void)n_in; (void)out_size; (void)ws_size;
    const float* class_preds = (const float*)d_in[0];
    const float* box_preds   = (const float*)d_in[1];
    const float* mask_coeffs = (const float*)d_in[2];
    const float* prototypes  = (const float*)d_in[3];
    const float* anchors     = (const float*)d_in[4];
    const float* gt_boxes    = (const float*)d_in[5];
    const int*   gt_labels   = (const int*)d_in[6];
    const float* gt_masks    = (const float*)d_in[7];
    float* out = (float*)d_out;

    size_t off = 0;
    char* w = (char*)d_ws;
    auto take = [&](size_t bytes) -> char* {
        char* p = w + off;
        off += (bytes + 255) & ~(size_t)255;
        return p;
    };
    float* acc      = (float*)take(32);                       // [.,.,., npos(int)]
    float* best_iou = (float*)take((size_t)BB * AA * 4);
    int*   best_g   = (int*)  take((size_t)BB * AA * 4);
    int*   gidx     = (int*)  take((size_t)BB * AA * 4);
    int*   selmask  = (int*)  take((size_t)BB * AA * 4);
    unsigned long long* gkey_part =
        (unsigned long long*)take((size_t)BB * NB1 * GG * 8);
    int*   pos_cnt  = (int*)  take((size_t)BB * 4);
    unsigned long long* pos_key = (unsigned long long*)take((size_t)BB * AA * 8);
    int*   sel_g    = (int*)  take((size_t)BB * KPOS * 4);
    int*   sel_cnt  = (int*)  take((size_t)BB * 4);
    _Float16* sel_coef = (_Float16*)take((size_t)BB * KPOS * PP * 2);
    int*   act_list = (int*)  take((size_t)BB * AA * 4);
    int*   act_cnt  = (int*)  take((size_t)BB * 4);
    _Float16* protoT = (_Float16*)take((size_t)BB * PHW * PP * 2);
    unsigned* pmaskb = (unsigned*)take((size_t)BB * PHW * 4);
    float* part_cls  = (float*)take((size_t)BB * NB45 * 4);
    float* part_box  = (float*)take((size_t)BB * NB45 * 4);
    float* part_mask = (float*)take((size_t)BB * NB7 * 4);

    k01<<<dim3(NB1 + NB0, BB), 256, 0, stream>>>(
        anchors, gt_boxes, prototypes, gt_masks,
        best_iou, best_g, gkey_part, acc, protoT, pmaskb);
    k3_match_scan<<<BB, 1024, 0, stream>>>(
        best_iou, best_g, gkey_part, gt_labels, gidx, selmask, pos_key, pos_cnt,
        (int*)(acc + 3), act_list, act_cnt);
    k456<<<dim3(NB45 + 1, BB), 1024, 0, stream>>>(
        class_preds, act_list, act_cnt, box_preds, anchors, gt_boxes,
        part_cls, part_box,
        pos_key, pos_cnt, gidx, mask_coeffs, sel_g, sel_coef, sel_cnt);
    k7_mask<<<dim3(NB7, BB), 256, 0, stream>>>(
        protoT, pmaskb, sel_coef, sel_g, sel_cnt, part_mask);
    k8_final<<<1, 1024, 0, stream>>>(
        part_cls, part_box, part_mask, (int*)(acc + 3), out);
}

// Round 17
// 71.957 us; speedup vs baseline: 1.8065x; 1.0285x over previous
//
#include <hip/hip_runtime.h>
#include <math.h>

#define BB 8
#define AA 19248
#define GG 32
#define CC 81
#define PP 32
#define PHW 19044   /* 138*138 */
#define KPOS 128
#define NEGRATIO 3
#define SELCAP 7680
#define NWCH 304    /* 19 outer iters x 16 waves of 64 anchors */
#define NB1 76      /* k1-role blocks per image = ceil(AA/256) */
#define NB0 75      /* k0-role blocks per image = ceil(PHW/256) */
#define NPT 1191    /* pixel tiles of 16 = ceil(PHW/16) */
#define NB7 298     /* k7-role blocks per image = ceil(NPT/4) */
#define NB45 24     /* k45-role blocks per image (256 threads each) */

typedef _Float16 half8 __attribute__((ext_vector_type(8)));
typedef float floatx4 __attribute__((ext_vector_type(4)));

// ---------------------------------------------------------------------------
// IoU helper — contraction off so every recomputation produces bitwise-
// identical values and FMA fusion can't flip threshold/argmax decisions.
// ---------------------------------------------------------------------------
__device__ __forceinline__ float iou_one(float ax1, float ay1, float ax2, float ay2,
                                         float areaA,
                                         float gx1, float gy1, float gx2, float gy2) {
#pragma clang fp contract(off)
    float ix1 = fmaxf(ax1, gx1), iy1 = fmaxf(ay1, gy1);
    float ix2 = fminf(ax2, gx2), iy2 = fminf(ay2, gy2);
    float iw = fmaxf(ix2 - ix1, 0.0f), ih = fmaxf(iy2 - iy1, 0.0f);
    float inter = iw * ih;
    float areaB = (gx2 - gx1) * (gy2 - gy1);
    float u = areaA + areaB - inter;
    u = fmaxf(u, 1e-6f);
    return inter / u;
}

// ---------------------------------------------------------------------------
// K01: FUSED prep + match (independent stages co-resident).
//   blockIdx.x <  NB1 : match role — per (b,a) best IoU + argmax + per-(b,g)
//                       best-anchor partial keys.
//   blockIdx.x >= NB1 : prep role — pack binary gt-masks into u32 + transpose
//                       protos to [b][px][32] f16.
// ---------------------------------------------------------------------------
__global__ __launch_bounds__(256) void k01(
    const float* __restrict__ anchors, const float* __restrict__ gt_boxes,
    const float* __restrict__ protos, const float* __restrict__ gtm,
    float* __restrict__ best_iou, int* __restrict__ best_g,
    unsigned long long* __restrict__ gkey_part, float* __restrict__ acc,
    _Float16* __restrict__ protoT, unsigned* __restrict__ pmask) {
#pragma clang fp contract(off)
    int b = blockIdx.y;
    __shared__ float sg[GG][4];
    __shared__ unsigned long long s_gk[GG];

    if (blockIdx.x >= NB1) {
        // ---- prep role ----
        int px = (blockIdx.x - NB1) * 256 + threadIdx.x;
        if (px >= PHW) return;
        const float* pb = protos + (size_t)b * PP * PHW + px;
        _Float16 v[PP];
        #pragma unroll
        for (int k = 0; k < PP; ++k)
            v[k] = (_Float16)pb[(size_t)k * PHW];
        half8* dst = (half8*)&protoT[((size_t)b * PHW + px) * PP];
        #pragma unroll
        for (int q = 0; q < 4; ++q)
            dst[q] = *(half8*)&v[q * 8];
        const float* gb = gtm + (size_t)b * GG * PHW + px;
        unsigned m = 0u;
        #pragma unroll
        for (int g = 0; g < GG; ++g)
            m |= (gb[(size_t)g * PHW] > 0.5f) ? (1u << g) : 0u;
        pmask[(size_t)b * PHW + px] = m;
        return;
    }

    // ---- match role ----
    int a = blockIdx.x * 256 + threadIdx.x;
    int lane = threadIdx.x & 63;
    if (blockIdx.x == 0 && b == 0 && threadIdx.x < 4)
        ((int*)acc)[threadIdx.x] = 0;            // zero [., ., ., npos]
    for (int t = threadIdx.x; t < GG * 4; t += 256)
        sg[t >> 2][t & 3] = gt_boxes[b * GG * 4 + t] / 550.0f;
    if (threadIdx.x < GG) s_gk[threadIdx.x] = 0ULL;
    __syncthreads();
    bool valid = a < AA;
    int ac = valid ? a : AA - 1;
    float4 an = ((const float4*)anchors)[ac];
    float ax1 = an.x - an.z * 0.5f, ay1 = an.y - an.w * 0.5f;
    float ax2 = an.x + an.z * 0.5f, ay2 = an.y + an.w * 0.5f;
    float areaA = (ax2 - ax1) * (ay2 - ay1);
    unsigned long long bk = 0ULL;   // (vbits<<6)|(31-g): max => first-max argmax
    for (int gg = 0; gg < GG; ++gg) {
        int g = (gg + lane) & (GG - 1);          // stagger: 32 distinct LDS slots
        float v = iou_one(ax1, ay1, ax2, ay2, areaA, sg[g][0], sg[g][1], sg[g][2], sg[g][3]);
        unsigned vb = __float_as_uint(v);        // v >= 0 -> order-preserving
        unsigned long long k2 = ((unsigned long long)vb << 6) | (unsigned)(GG - 1 - g);
        if (k2 > bk) bk = k2;
        if (valid) {
            unsigned long long kg =
                ((unsigned long long)vb << 32) | (unsigned)(AA - 1 - a);
            atomicMax(&s_gk[g], kg);
        }
    }
    if (valid) {
        best_iou[b * AA + a] = __uint_as_float((unsigned)(bk >> 6));
        best_g[b * AA + a] = (GG - 1) - (int)(bk & 63ULL);
    }
    __syncthreads();
    if (threadIdx.x < GG)
        gkey_part[((size_t)b * NB1 + blockIdx.x) * GG + threadIdx.x] = s_gk[threadIdx.x];
}

// ---------------------------------------------------------------------------
// K36: FUSED k3 (match-scan) + k6 (top-K radix select) — k6's block b
// consumes only what k3's block b produced (pos_key slots, npos, gidx);
// same-block global write -> __syncthreads -> read is coherent, so the two
// phases run sequentially in ONE kernel. LDS total ~108 KB (< 160 KB).
// act_list entries PACKED: a | g<<15 | lbl<<20 | pos<<31. Emits f16 coeffs
// zero-padded to KPOS rows + monotone-padded sel_g for K7's MFMA path.
// ---------------------------------------------------------------------------
__global__ __launch_bounds__(1024) void k36(
    const float* __restrict__ best_iou, const int* __restrict__ best_g_in,
    const unsigned long long* __restrict__ gkey_part, const int* __restrict__ gtl,
    int* __restrict__ gidx_out, int* __restrict__ selmask,
    unsigned long long* __restrict__ pos_key,
    int* __restrict__ pos_cnt, int* __restrict__ g_npos,
    int* __restrict__ act_list, int* __restrict__ act_cnt,
    const float* __restrict__ coeffs,
    int* __restrict__ sel_g, _Float16* __restrict__ sel_coef,
    int* __restrict__ sel_cnt) {
#pragma clang fp contract(off)
    int b = blockIdx.x;
    int tid = threadIdx.x;
    int lane = tid & 63, wid = tid >> 6;
    __shared__ short s_ov[AA];                  // override g per anchor, -1 none
    __shared__ unsigned long long s_gmax[GG];
    __shared__ int sba[GG];
    __shared__ int s_gtl[GG];
    __shared__ unsigned long long s_pmask[NWCH];
    __shared__ unsigned long long s_nmask[NWCH];
    __shared__ int s_woff[NWCH];
    __shared__ int s_wred[5];
    __shared__ int s_cnt, s_act;
    // k6-phase LDS
    __shared__ unsigned long long s_keys[SELCAP];
    __shared__ int s_hist[256];
    __shared__ int s_sfx[256];
    __shared__ int s_wsum[4];
    __shared__ unsigned long long s_prefix;
    __shared__ int s_kk;
    __shared__ int s_nsel;
    __shared__ int s_sel_a[KPOS];
    __shared__ int s_sorted_a[KPOS];
    __shared__ int s_sorted_g[KPOS];
    __shared__ int s_gcnt[GG];

    for (int i = tid; i < AA; i += 1024) s_ov[i] = -1;
    if (tid < GG) { s_gmax[tid] = 0ULL; s_gtl[tid] = gtl[b * GG + tid]; }
    if (tid == 0) { s_cnt = 0; s_act = 0; s_prefix = 0ULL; s_kk = KPOS; s_nsel = 0; }
    __syncthreads();
    // reduce 76 per-block partial keys per g (32 g x 32 groups)
    for (int c = tid >> 5; c < NB1; c += 32)
        atomicMax(&s_gmax[tid & 31],
                  gkey_part[((size_t)b * NB1 + c) * GG + (tid & 31)]);
    __syncthreads();
    if (tid < GG) sba[tid] = AA - 1 - (int)(unsigned)(s_gmax[tid] & 0xffffffffULL);
    __syncthreads();
    if (tid == 0) {
        for (int g = 0; g < GG; ++g) s_ov[sba[g]] = (short)g;  // ascending: last wins
    }
    __syncthreads();

    // ---- k3 pass 1: decisions + pos keys (global AND LDS mirror) + ballots
    for (int base = 0; base < AA; base += 1024) {
        int a = base + tid;
        bool p = false, npre = false;
        if (a < AA) {
            float biou = best_iou[b * AA + a];
            int ov = s_ov[a];
            int gi = (ov >= 0) ? ov : best_g_in[b * AA + a];
            p = (biou >= 0.5f) || (ov >= 0);
            npre = (biou < 0.4f) && !p;
            gidx_out[b * AA + a] = gi;
            selmask[b * AA + a] = p ? 2 : (npre ? 1 : 0);
            if (p) {
                int slot = atomicAdd(&s_cnt, 1);
                unsigned vb = __float_as_uint(biou + 1.0f);   // >= 0x3F800000
                unsigned long long key =
                    ((unsigned long long)(vb - 0x3F800000u) << 32) |
                    (unsigned)(AA - 1 - a);
                pos_key[(size_t)b * AA + slot] = key;
                if (slot < SELCAP) s_keys[slot] = key;
            }
        }
        unsigned long long pm = __ballot(p);
        unsigned long long nm = __ballot(npre);
        if (lane == 0) {
            int w = (base >> 6) + wid;
            s_pmask[w] = pm;
            s_nmask[w] = nm;
        }
    }
    __syncthreads();
    int npos = s_cnt;
    if (tid == 0) { pos_cnt[b] = npos; atomicAdd(g_npos, npos); }
    int cap = npos * NEGRATIO;

    // scan 304 chunk counts with 5 waves
    int c = (tid < NWCH) ? __popcll(s_nmask[tid]) : 0;
    int inc = c;
    if (wid < 5) {
        #pragma unroll
        for (int d = 1; d < 64; d <<= 1) {
            int t = __shfl_up(inc, d);
            if (lane >= d) inc += t;
        }
        if (lane == 63) s_wred[wid] = inc;
    }
    __syncthreads();
    if (tid == 0) {
        int run = 0;
        #pragma unroll
        for (int i = 0; i < 5; ++i) { int t = s_wred[i]; s_wred[i] = run; run += t; }
    }
    __syncthreads();
    if (tid < NWCH) s_woff[tid] = inc - c + s_wred[wid];   // exclusive prefix
    __syncthreads();

    // ---- k3 pass 2: drop negs beyond cap, compact PACKED active rows
    for (int base = 0; base < AA; base += 1024) {
        int a = base + tid;
        int w = (base >> 6) + wid;
        unsigned long long nm = s_nmask[w], pm = s_pmask[w];
        bool npre = (nm >> lane) & 1ULL;
        bool pos  = (pm >> lane) & 1ULL;
        int rank = __popcll(nm & ((1ULL << lane) - 1ULL));
        bool kept = npre && (s_woff[w] + rank + 1 <= cap);
        if (a < AA) {
            if (npre && !kept) selmask[b * AA + a] = 0;
            if (pos || kept) {
                int slot = atomicAdd(&s_act, 1);
                int gi = gidx_out[b * AA + a];          // same-block write, L1
                int lbl = pos ? s_gtl[gi] : 0;
                unsigned e = (unsigned)a | ((unsigned)gi << 15) |
                             ((unsigned)lbl << 20) | (pos ? 0x80000000u : 0u);
                act_list[b * AA + slot] = (int)e;
            }
        }
    }
    __syncthreads();
    if (tid == 0) act_cnt[b] = s_act;

    // ================= k6 phase (same block, same image) =================
    int n = npos;
    int K = (n < KPOS) ? n : KPOS;
    const unsigned long long* keys =
        (n <= SELCAP) ? s_keys : (pos_key + (size_t)b * AA);
    __syncthreads();

    if (n > KPOS) {
        for (int d = 6; d >= 0; --d) {
            unsigned long long pref = s_prefix;   // snapshot (post-barrier)
            int kk = s_kk;
            if (tid < 256) s_hist[tid] = 0;
            __syncthreads();
            unsigned long long mhi = ~((1ULL << (8 * (d + 1))) - 1ULL);
            for (int i = tid; i < n; i += 1024) {
                unsigned long long k = keys[i];
                if ((k & mhi) == pref)
                    atomicAdd(&s_hist[(int)((k >> (8 * d)) & 255)], 1);
            }
            __syncthreads();
            int x = 0;
            if (tid < 256) {
                x = s_hist[255 - tid];
                #pragma unroll
                for (int o = 1; o < 64; o <<= 1) {
                    int t = __shfl_up(x, o);
                    if (lane >= o) x += t;
                }
                if (lane == 63) s_wsum[tid >> 6] = x;
            }
            __syncthreads();
            if (tid == 0) {
                int run = 0;
                #pragma unroll
                for (int i = 0; i < 4; ++i) { int t = s_wsum[i]; s_wsum[i] = run; run += t; }
            }
            __syncthreads();
            if (tid < 256) s_sfx[255 - tid] = x + s_wsum[tid >> 6];
            __syncthreads();
            if (tid < 256) {
                int v = tid;
                int ge = s_sfx[v];
                int gt = (v == 255) ? 0 : s_sfx[v + 1];
                if (ge >= kk && gt < kk) {
                    s_prefix = pref | ((unsigned long long)v << (8 * d));
                    s_kk = kk - gt;
                }
            }
            __syncthreads();
        }
    }

    unsigned long long T = (n > KPOS) ? s_prefix : 0ULL;
    for (int i = tid; i < n; i += 1024) {
        unsigned long long k = keys[i];
        if (k >= T) {
            int slot = atomicAdd(&s_nsel, 1);
            if (slot < KPOS)
                s_sel_a[slot] = AA - 1 - (int)(unsigned)(k & 0xffffffffu);
        }
    }
    __syncthreads();

    if (tid < GG) s_gcnt[tid] = 0;
    __syncthreads();
    int mya = -1, myg = -1;
    if (tid < K) {
        mya = s_sel_a[tid];
        myg = gidx_out[b * AA + mya];
        atomicAdd(&s_gcnt[myg], 1);
    }
    __syncthreads();
    if (tid == 0) {
        int run = 0;
        for (int g = 0; g < GG; ++g) { int cg = s_gcnt[g]; s_gcnt[g] = run; run += cg; }
    }
    __syncthreads();
    if (tid < K) {
        int pos = atomicAdd(&s_gcnt[myg], 1);
        s_sorted_a[pos] = mya;
        s_sorted_g[pos] = myg;
    }
    __syncthreads();

    if (tid == 0) sel_cnt[b] = K;
    int glast = (K > 0) ? s_sorted_g[K - 1] : 0;
    for (int t = tid; t < KPOS * PP; t += 1024) {
        int k = t >> 5, p = t & 31;
        _Float16 v = (_Float16)0.0f;
        if (k < K) {
            int a = s_sorted_a[k];
            v = (_Float16)coeffs[((size_t)(b * AA + a)) * PP + p];
        }
        sel_coef[(size_t)(b * KPOS + k) * PP + p] = v;
    }
    for (int t = tid; t < KPOS; t += 1024)
        sel_g[b * KPOS + t] = (t < K) ? s_sorted_g[t] : glast;
}

// ---------------------------------------------------------------------------
// K457: FUSED k45 (focal+box, thread-per-row) + k7 (MFMA mask loss) — both
// depend only on k36; role-split so the exp-heavy cls pass overlaps the
// MFMA mask pass.
//   blockIdx.x <  NB45 : k45 role.
//   blockIdx.x >= NB45 : k7 role.
// ---------------------------------------------------------------------------
__global__ __launch_bounds__(256) void k457(
    const float* __restrict__ cls_p, const int* __restrict__ act_list,
    const int* __restrict__ act_cnt, const float* __restrict__ box_p,
    const float* __restrict__ anchors, const float* __restrict__ gt_boxes,
    float* __restrict__ part_cls, float* __restrict__ part_box,
    const _Float16* __restrict__ protoT, const unsigned* __restrict__ pmask,
    const _Float16* __restrict__ sel_coef, const int* __restrict__ sel_g,
    const int* __restrict__ sel_cnt, float* __restrict__ part_mask) {
    int b = blockIdx.y;
    int tid = threadIdx.x;

    if (blockIdx.x < NB45) {
        // ---- k45 role ----
        int n = act_cnt[b];
        float fsum = 0.0f, bsum = 0.0f;
        for (int i = blockIdx.x * 256 + tid; i < n; i += NB45 * 256) {
            unsigned e = (unsigned)act_list[b * AA + i];
            int a = e & 0x7fff;
            int g = (e >> 15) & 31;
            int lbl = (e >> 20) & 127;
            bool pos = (e >> 31) != 0u;
            const float* x = cls_p + (size_t)(b * AA + a) * CC;
            float v80 = x[80];
            float m0 = v80, m1 = -3.0e38f, m2 = -3.0e38f, m3 = -3.0e38f;
            #pragma unroll
            for (int q = 0; q < 20; ++q) {
                m0 = fmaxf(m0, x[4 * q + 0]); m1 = fmaxf(m1, x[4 * q + 1]);
                m2 = fmaxf(m2, x[4 * q + 2]); m3 = fmaxf(m3, x[4 * q + 3]);
            }
            float m = fmaxf(fmaxf(m0, m1), fmaxf(m2, m3));
            float s0 = __expf(v80 - m), s1 = 0.f, s2 = 0.f, s3 = 0.f;
            #pragma unroll
            for (int q = 0; q < 20; ++q) {
                s0 += __expf(x[4 * q + 0] - m); s1 += __expf(x[4 * q + 1] - m);
                s2 += __expf(x[4 * q + 2] - m); s3 += __expf(x[4 * q + 3] - m);
            }
            float s = (s0 + s1) + (s2 + s3);
            float pt = __expf(x[lbl] - m) / s;
            pt = fminf(fmaxf(pt, 1e-6f), 1.0f - 1e-6f);
            float at = (lbl > 0) ? 0.25f : 0.75f;
            float om = 1.0f - pt;
            fsum += at * om * om * (-__logf(pt));
            if (pos) {
#pragma clang fp contract(off)
                float4 mb = ((const float4*)gt_boxes)[b * GG + g];
                float4 an = ((const float4*)anchors)[a];
                const float4 bp = ((const float4*)box_p)[(size_t)b * AA + a];
                float q0 = mb.x / 550.0f, q1 = mb.y / 550.0f;
                float q2 = mb.z / 550.0f, q3 = mb.w / 550.0f;
                float gcx = 0.5f * (q0 + q2), gcy = 0.5f * (q1 + q3);
                float gw = fmaxf(q2 - q0, 1e-6f), gh = fmaxf(q3 - q1, 1e-6f);
                float t0 = (gcx - an.x) / (an.z * 0.1f);
                float t1 = (gcy - an.y) / (an.w * 0.1f);
                float t2 = logf(gw / an.z) / 0.2f;
                float t3 = logf(gh / an.w) / 0.2f;
                float d;
                d = fabsf(bp.x - t0); bsum += (d < 1.0f) ? 0.5f * d * d : d - 0.5f;
                d = fabsf(bp.y - t1); bsum += (d < 1.0f) ? 0.5f * d * d : d - 0.5f;
                d = fabsf(bp.z - t2); bsum += (d < 1.0f) ? 0.5f * d * d : d - 0.5f;
                d = fabsf(bp.w - t3); bsum += (d < 1.0f) ? 0.5f * d * d : d - 0.5f;
            }
        }
        for (int off = 32; off; off >>= 1) {
            fsum += __shfl_xor(fsum, off);
            bsum += __shfl_xor(bsum, off);
        }
        __shared__ float s4f[4], s4b[4];
        if ((tid & 63) == 0) { s4f[tid >> 6] = fsum; s4b[tid >> 6] = bsum; }
        __syncthreads();
        if (tid == 0) {
            part_cls[b * NB45 + blockIdx.x] = s4f[0] + s4f[1] + s4f[2] + s4f[3];
            part_box[b * NB45 + blockIdx.x] = s4b[0] + s4b[1] + s4b[2] + s4b[3];
        }
        return;
    }

    // ---- k7 role ----
    int nk = sel_cnt[b];
    int wave = tid >> 6, lane = tid & 63;
    int lg = lane >> 4;                       // lane group 0..3
    int ln = lane & 15;                       // n (px) / A-row (k) index
    int pt = (blockIdx.x - NB45) * 4 + wave;  // pixel-tile index
    int px = pt * 16 + ln;
    bool pxv = (pt < NPT) && (px < PHW);
    int pc = pxv ? px : PHW - 1;

    half8 bfrag = *(const half8*)&protoT[((size_t)b * PHW + pc) * PP + lg * 8];
    unsigned gmask = pmask[(size_t)b * PHW + pc];

    const _Float16* ca = sel_coef + (size_t)b * KPOS * PP;
    const int* gb = sel_g + b * KPOS;

    half8 af[8];
    int4 gv[8];
    #pragma unroll
    for (int kt = 0; kt < 8; ++kt) {
        af[kt] = *(const half8*)&ca[(size_t)(kt * 16 + ln) * PP + lg * 8];
        gv[kt] = *(const int4*)&gb[kt * 16 + lg * 4];
    }

    float acc = 0.0f;
    #pragma unroll
    for (int kt = 0; kt < 8; ++kt) {
        floatx4 c = {0.f, 0.f, 0.f, 0.f};
        c = __builtin_amdgcn_mfma_f32_16x16x32_f16(af[kt], bfrag, c, 0, 0, 0);
        #pragma unroll
        for (int r = 0; r < 4; ++r) {
            int k = kt * 16 + lg * 4 + r;
            float l = c[r];
            int g0 = (r == 0) ? gv[kt].x : (r == 1) ? gv[kt].y
                   : (r == 2) ? gv[kt].z : gv[kt].w;
            float t = (float)((gmask >> g0) & 1u);
            float bce = fmaxf(l, 0.f) - l * t + __logf(1.f + __expf(-fabsf(l)));
            if (pxv && k < nk) acc += bce;
        }
    }

    for (int off = 32; off; off >>= 1) acc += __shfl_xor(acc, off);
    __shared__ float s_red[4];
    if (lane == 0) s_red[wave] = acc;
    __syncthreads();
    if (tid == 0)
        part_mask[(size_t)b * NB7 + (blockIdx.x - NB45)] =
            s_red[0] + s_red[1] + s_red[2] + s_red[3];
}

// ---------------------------------------------------------------------------
// K8: final reduction over all per-block partials.
// ---------------------------------------------------------------------------
__global__ __launch_bounds__(1024) void k8_final(
    const float* __restrict__ part_cls, const float* __restrict__ part_box,
    const float* __restrict__ part_mask, const int* __restrict__ npos,
    float* __restrict__ out) {
    int tid = threadIdx.x;
    float c = 0.f, bx = 0.f, mk = 0.f;
    for (int i = tid; i < NB45 * BB; i += 1024) {
        c += part_cls[i];
        bx += part_box[i];
    }
    for (int i = tid; i < NB7 * BB; i += 1024)
        mk += part_mask[i];
    for (int off = 32; off; off >>= 1) {
        c += __shfl_xor(c, off);
        bx += __shfl_xor(bx, off);
        mk += __shfl_xor(mk, off);
    }
    __shared__ float sc[16], sb[16], sm[16];
    if ((tid & 63) == 0) {
        sc[tid >> 6] = c; sb[tid >> 6] = bx; sm[tid >> 6] = mk;
    }
    __syncthreads();
    if (tid == 0) {
        float tc = 0.f, tb = 0.f, tm = 0.f;
        #pragma unroll
        for (int i = 0; i < 16; ++i) { tc += sc[i]; tb += sb[i]; tm += sm[i]; }
        float denom = fmaxf((float)(*npos), 1.0f);
        out[0] = (1.0f * tc + 1.5f * tb + 6.125f * (tm / (float)PHW)) / denom;
    }
}

// ---------------------------------------------------------------------------
extern "C" void kernel_launch(void* const* d_in, const int* in_sizes, int n_in,
                              void* d_out, int out_size, void* d_ws, size_t ws_size,
                              hipStream_t stream) {
    (void)in_sizes; (void)n_in; (void)out_size; (void)ws_size;
    const float* class_preds = (const float*)d_in[0];
    const float* box_preds   = (const float*)d_in[1];
    const float* mask_coeffs = (const float*)d_in[2];
    const float* prototypes  = (const float*)d_in[3];
    const float* anchors     = (const float*)d_in[4];
    const float* gt_boxes    = (const float*)d_in[5];
    const int*   gt_labels   = (const int*)d_in[6];
    const float* gt_masks    = (const float*)d_in[7];
    float* out = (float*)d_out;

    size_t off = 0;
    char* w = (char*)d_ws;
    auto take = [&](size_t bytes) -> char* {
        char* p = w + off;
        off += (bytes + 255) & ~(size_t)255;
        return p;
    };
    float* acc      = (float*)take(32);                       // [.,.,., npos(int)]
    float* best_iou = (float*)take((size_t)BB * AA * 4);
    int*   best_g   = (int*)  take((size_t)BB * AA * 4);
    int*   gidx     = (int*)  take((size_t)BB * AA * 4);
    int*   selmask  = (int*)  take((size_t)BB * AA * 4);
    unsigned long long* gkey_part =
        (unsigned long long*)take((size_t)BB * NB1 * GG * 8);
    int*   pos_cnt  = (int*)  take((size_t)BB * 4);
    unsigned long long* pos_key = (unsigned long long*)take((size_t)BB * AA * 8);
    int*   sel_g    = (int*)  take((size_t)BB * KPOS * 4);
    int*   sel_cnt  = (int*)  take((size_t)BB * 4);
    _Float16* sel_coef = (_Float16*)take((size_t)BB * KPOS * PP * 2);
    int*   act_list = (int*)  take((size_t)BB * AA * 4);
    int*   act_cnt  = (int*)  take((size_t)BB * 4);
    _Float16* protoT = (_Float16*)take((size_t)BB * PHW * PP * 2);
    unsigned* pmaskb = (unsigned*)take((size_t)BB * PHW * 4);
    float* part_cls  = (float*)take((size_t)BB * NB45 * 4);
    float* part_box  = (float*)take((size_t)BB * NB45 * 4);
    float* part_mask = (float*)take((size_t)BB * NB7 * 4);

    k01<<<dim3(NB1 + NB0, BB), 256, 0, stream>>>(
        anchors, gt_boxes, prototypes, gt_masks,
        best_iou, best_g, gkey_part, acc, protoT, pmaskb);
    k36<<<BB, 1024, 0, stream>>>(
        best_iou, best_g, gkey_part, gt_labels, gidx, selmask, pos_key, pos_cnt,
        (int*)(acc + 3), act_list, act_cnt,
        mask_coeffs, sel_g, sel_coef, sel_cnt);
    k457<<<dim3(NB45 + NB7, BB), 256, 0, stream>>>(
        class_preds, act_list, act_cnt, box_preds, anchors, gt_boxes,
        part_cls, part_box,
        protoT, pmaskb, sel_coef, sel_g, sel_cnt, part_mask);
    k8_final<<<1, 1024, 0, stream>>>(
        part_cls, part_box, part_mask, (int*)(acc + 3), out);
}